// Round 1
// baseline (1044.190 us; speedup 1.0000x reference)
//
#include <hip/hip_runtime.h>
#include <math.h>

#define NG 256   // NUM_GRAPHS

// ---------------------------------------------------------------------------
// deg[c] += 1 for each edge target c  (self-loop +1 folded into dinv kernel)
__global__ void deg_kernel(const int* __restrict__ col, float* __restrict__ deg, int E) {
    int e = blockIdx.x * blockDim.x + threadIdx.x;
    if (e < E) atomicAdd(&deg[col[e]], 1.0f);
}

// deg -> dinv = rsqrt(deg + 1)   (in place)
__global__ void dinv_kernel(float* __restrict__ deg, int N) {
    int i = blockIdx.x * blockDim.x + threadIdx.x;
    if (i < N) deg[i] = rsqrtf(deg[i] + 1.0f);
}

// hs[i][f] = (sum_k x[i][k] * W[k][f]) * dinv[i]   (Fin=32, Fout=32)
__global__ __launch_bounds__(256) void hs1_kernel(
        const float* __restrict__ x, const float* __restrict__ W,
        const float* __restrict__ dinv, float* __restrict__ hs, int N) {
    __shared__ float Ws[32 * 32];
    for (int t = threadIdx.x; t < 1024; t += blockDim.x) Ws[t] = W[t];
    __syncthreads();
    int gid = blockIdx.x * blockDim.x + threadIdx.x;
    if (gid >= N * 32) return;
    int i = gid >> 5, f = gid & 31;
    const float* xr = x + (size_t)i * 32;
    float acc = 0.f;
#pragma unroll
    for (int k = 0; k < 32; k++) acc += xr[k] * Ws[k * 32 + f];
    hs[gid] = acc * dinv[i];
}

// hs2[i][f] = (sum_k h1[i][k] * W2[k][f]) * dinv[i]   (Fin=32, Fout=24)
__global__ __launch_bounds__(256) void hs2_kernel(
        const float* __restrict__ h1, const float* __restrict__ W2,
        const float* __restrict__ dinv, float* __restrict__ hs2, int N) {
    __shared__ float Ws[32 * 24];
    for (int t = threadIdx.x; t < 768; t += blockDim.x) Ws[t] = W2[t];
    __syncthreads();
    int gid = blockIdx.x * blockDim.x + threadIdx.x;
    if (gid >= N * 24) return;
    int i = gid / 24, f = gid - i * 24;
    const float* hr = h1 + (size_t)i * 32;
    float acc = 0.f;
#pragma unroll
    for (int k = 0; k < 32; k++) acc += hr[k] * Ws[k * 24 + f];
    hs2[gid] = acc * dinv[i];
}

// acc[col[e]][f] += hs[row[e]][f]  for every edge, feature
template <int F>
__global__ __launch_bounds__(256) void scatter_kernel(
        const int* __restrict__ ei, const float* __restrict__ hs,
        float* __restrict__ acc, int E) {
    int gid = blockIdx.x * blockDim.x + threadIdx.x;
    if (gid >= E * F) return;
    int e = gid / F, f = gid - e * F;
    int r = ei[e];        // source
    int c = ei[E + e];    // target
    atomicAdd(&acc[(size_t)c * F + f], hs[(size_t)r * F + f]);
}

// out = relu(dinv[i]*(acc + hs) + b[f])   (self-loop term = +hs)
template <int F>
__global__ __launch_bounds__(256) void finalize_kernel(
        const float* __restrict__ hs, const float* __restrict__ acc_in,
        const float* __restrict__ dinv, const float* __restrict__ b,
        float* __restrict__ out, int N) {
    int gid = blockIdx.x * blockDim.x + threadIdx.x;
    if (gid >= N * F) return;
    int i = gid / F, f = gid - i * F;
    float v = dinv[i] * (acc_in[gid] + hs[gid]) + b[f];
    out[gid] = fmaxf(v, 0.f);
}

// v[i] = relu(h2[i] @ Wn1 + bn1) @ Wn2 + bn2
__global__ __launch_bounds__(256) void nlogit_kernel(
        const float* __restrict__ h2,
        const float* __restrict__ Wn1, const float* __restrict__ bn1,
        const float* __restrict__ Wn2, const float* __restrict__ bn2,
        float* __restrict__ vout, int N) {
    __shared__ float Ws[24 * 16];
    __shared__ float b1s[16], W2s[16];
    __shared__ float b2s;
    for (int t = threadIdx.x; t < 384; t += blockDim.x) Ws[t] = Wn1[t];
    if (threadIdx.x < 16) { b1s[threadIdx.x] = bn1[threadIdx.x]; W2s[threadIdx.x] = Wn2[threadIdx.x]; }
    if (threadIdx.x == 0) b2s = bn2[0];
    __syncthreads();
    int i = blockIdx.x * blockDim.x + threadIdx.x;
    if (i >= N) return;
    float h[24];
    const float4* hr = (const float4*)(h2 + (size_t)i * 24);  // rows are 96B = 16B-aligned
#pragma unroll
    for (int q = 0; q < 6; q++) {
        float4 x4 = hr[q];
        h[4 * q] = x4.x; h[4 * q + 1] = x4.y; h[4 * q + 2] = x4.z; h[4 * q + 3] = x4.w;
    }
    float acc = b2s;
#pragma unroll
    for (int j = 0; j < 16; j++) {
        float u = b1s[j];
#pragma unroll
        for (int k = 0; k < 24; k++) u += h[k] * Ws[k * 16 + j];
        acc += fmaxf(u, 0.f) * W2s[j];
    }
    vout[i] = acc;
}

__device__ __forceinline__ int lower_bound_i(const int* __restrict__ a, int n, int key) {
    int lo = 0, hi = n;
    while (lo < hi) {
        int mid = (lo + hi) >> 1;
        if (a[mid] < key) lo = mid + 1; else hi = mid;
    }
    return lo;
}

// One block per graph (batch is sorted): segment softmax over nodes, mean pool,
// weighted pool, t-head, b-head pre-softmax. No global atomics.
__global__ __launch_bounds__(256) void graph_kernel(
        const float* __restrict__ v, const float* __restrict__ h2,
        const int* __restrict__ batch,
        const float* __restrict__ Wg, const float* __restrict__ bg,
        const float* __restrict__ Wt, const float* __restrict__ bt,
        const float* __restrict__ Wb1p, const float* __restrict__ bb1p,
        const float* __restrict__ Wb2p, const float* __restrict__ bb2p,
        float* __restrict__ out_t, float* __restrict__ out_n,
        float* __restrict__ bbpre, int N) {
    const int g = blockIdx.x;
    const int tid = threadIdx.x;
    const int lane = tid & 63;
    const int wid = tid >> 6;

    const int start = lower_bound_i(batch, N, g);
    const int end = lower_bound_i(batch, N, g + 1);

    __shared__ float sm[4];
    __shared__ float part[4][49];

    // pass A: max of v over the segment
    float m = -INFINITY;
    for (int idx = start + tid; idx < end; idx += 256) m = fmaxf(m, v[idx]);
#pragma unroll
    for (int off = 32; off > 0; off >>= 1) m = fmaxf(m, __shfl_down(m, off, 64));
    if (lane == 0) sm[wid] = m;
    __syncthreads();
    m = fmaxf(fmaxf(sm[0], sm[1]), fmaxf(sm[2], sm[3]));

    // pass B: s = sum exp(v-m); hsum = sum h2; wsum = sum exp(v-m)*h2
    float s = 0.f;
    float hsum[24], wsum[24];
#pragma unroll
    for (int f = 0; f < 24; f++) { hsum[f] = 0.f; wsum[f] = 0.f; }
    for (int idx = start + tid; idx < end; idx += 256) {
        float e = __expf(v[idx] - m);
        s += e;
        const float4* hr = (const float4*)(h2 + (size_t)idx * 24);
#pragma unroll
        for (int q = 0; q < 6; q++) {
            float4 x4 = hr[q];
            hsum[4 * q] += x4.x;  wsum[4 * q] += e * x4.x;
            hsum[4 * q + 1] += x4.y; wsum[4 * q + 1] += e * x4.y;
            hsum[4 * q + 2] += x4.z; wsum[4 * q + 2] += e * x4.z;
            hsum[4 * q + 3] += x4.w; wsum[4 * q + 3] += e * x4.w;
        }
    }
#pragma unroll
    for (int off = 32; off > 0; off >>= 1) {
        s += __shfl_down(s, off, 64);
#pragma unroll
        for (int f = 0; f < 24; f++) {
            hsum[f] += __shfl_down(hsum[f], off, 64);
            wsum[f] += __shfl_down(wsum[f], off, 64);
        }
    }
    if (lane == 0) {
        part[wid][0] = s;
#pragma unroll
        for (int f = 0; f < 24; f++) { part[wid][1 + f] = hsum[f]; part[wid][25 + f] = wsum[f]; }
    }
    __syncthreads();
    const float stot = part[0][0] + part[1][0] + part[2][0] + part[3][0];
    const float invs = (stot > 0.f) ? 1.f / stot : 0.f;

    // pass C: write normalized per-node softmax
    for (int idx = start + tid; idx < end; idx += 256)
        out_n[idx] = __expf(v[idx] - m) * invs;

    // graph-level heads on thread 0 (tiny)
    if (tid == 0) {
        float hsumT[24], wsumT[24];
#pragma unroll
        for (int f = 0; f < 24; f++) {
            hsumT[f] = part[0][1 + f] + part[1][1 + f] + part[2][1 + f] + part[3][1 + f];
            wsumT[f] = part[0][25 + f] + part[1][25 + f] + part[2][25 + f] + part[3][25 + f];
        }
        float cnt = (float)(end - start);
        float denom = fmaxf(cnt, 1.0f);

        // t head: g32 = mean @ Wg + bg ; t = softmax(g32 @ Wt + bt)
        float mean[24];
#pragma unroll
        for (int f = 0; f < 24; f++) mean[f] = hsumT[f] / denom;
        float gout[32];
        for (int o = 0; o < 32; o++) {
            float a = bg[o];
#pragma unroll
            for (int k = 0; k < 24; k++) a += mean[k] * Wg[k * 32 + o];
            gout[o] = a;
        }
        float t0 = bt[0], t1 = bt[1];
#pragma unroll
        for (int k = 0; k < 32; k++) { t0 += gout[k] * Wt[k * 2]; t1 += gout[k] * Wt[k * 2 + 1]; }
        float tm = fmaxf(t0, t1);
        float e0 = __expf(t0 - tm), e1 = __expf(t1 - tm);
        float ts = e0 + e1;
        out_t[g * 2 + 0] = e0 / ts;
        out_t[g * 2 + 1] = e1 / ts;

        // b head pre-softmax: bf = wsum/s ; bbpre = relu(bf@Wb1+bb1)@Wb2+bb2
        float bf[24];
#pragma unroll
        for (int f = 0; f < 24; f++) bf[f] = wsumT[f] * invs;
        float u[16];
        for (int j = 0; j < 16; j++) {
            float a = bb1p[j];
#pragma unroll
            for (int k = 0; k < 24; k++) a += bf[k] * Wb1p[k * 16 + j];
            u[j] = fmaxf(a, 0.f);
        }
        for (int c = 0; c < 3; c++) {
            float a = bb2p[c];
#pragma unroll
            for (int j = 0; j < 16; j++) a += u[j] * Wb2p[j * 3 + c];
            bbpre[g * 3 + c] = a;
        }
    }
}

// column softmax over the 256 graphs (axis=0), 3 columns
__global__ __launch_bounds__(256) void bb_kernel(
        const float* __restrict__ bbpre, float* __restrict__ out_bb) {
    __shared__ float red[NG];
    int g = threadIdx.x;
#pragma unroll
    for (int c = 0; c < 3; c++) {
        float vv = bbpre[g * 3 + c];
        red[g] = vv;
        __syncthreads();
        for (int off = 128; off > 0; off >>= 1) {
            if (g < off) red[g] = fmaxf(red[g], red[g + off]);
            __syncthreads();
        }
        float m = red[0];
        __syncthreads();
        float e = __expf(vv - m);
        red[g] = e;
        __syncthreads();
        for (int off = 128; off > 0; off >>= 1) {
            if (g < off) red[g] += red[g + off];
            __syncthreads();
        }
        float ssum = red[0];
        __syncthreads();
        out_bb[g * 3 + c] = e / ssum;
    }
}

extern "C" void kernel_launch(void* const* d_in, const int* in_sizes, int n_in,
                              void* d_out, int out_size, void* d_ws, size_t ws_size,
                              hipStream_t stream) {
    const float* x   = (const float*)d_in[0];
    const int*   ei  = (const int*)d_in[1];    // [2,E] flat: row=ei[0..E), col=ei[E..2E)
    const int*   bat = (const int*)d_in[2];
    const float* W1  = (const float*)d_in[3];
    const float* b1  = (const float*)d_in[4];
    const float* W2  = (const float*)d_in[5];
    const float* b2  = (const float*)d_in[6];
    const float* Wg  = (const float*)d_in[7];
    const float* bg  = (const float*)d_in[8];
    const float* Wt  = (const float*)d_in[9];
    const float* bt  = (const float*)d_in[10];
    const float* Wn1 = (const float*)d_in[11];
    const float* bn1 = (const float*)d_in[12];
    const float* Wn2 = (const float*)d_in[13];
    const float* bn2 = (const float*)d_in[14];
    const float* Wb1 = (const float*)d_in[15];
    const float* bb1 = (const float*)d_in[16];
    const float* Wb2 = (const float*)d_in[17];
    const float* bb2 = (const float*)d_in[18];

    const int N = in_sizes[2];
    const int E = in_sizes[1] / 2;

    // workspace layout (floats): deg/dinv[N] | bufA[32N] | bufB[32N] | bufC[24N] | bbpre[768]
    float* ws    = (float*)d_ws;
    float* deg   = ws;
    float* bufA  = ws + (size_t)N;          // hs1, then hs2
    float* bufB  = ws + (size_t)33 * N;     // acc1 -> h1 -> h2
    float* bufC  = ws + (size_t)65 * N;     // acc2 -> v (node logits)
    float* bbpre = ws + (size_t)89 * N;

    float* out_t  = (float*)d_out;          // [256,2]
    float* out_n  = out_t + 2 * NG;         // [N,1]
    float* out_bb = out_t + 2 * NG + N;     // [256,3]

    hipMemsetAsync(deg, 0, (size_t)N * sizeof(float), stream);
    hipMemsetAsync(bufB, 0, (size_t)56 * N * sizeof(float), stream);  // acc1 (32N) + acc2 (24N)

    const int B = 256;
    deg_kernel<<<(E + B - 1) / B, B, 0, stream>>>(ei + E, deg, E);
    dinv_kernel<<<(N + B - 1) / B, B, 0, stream>>>(deg, N);

    // layer 1: 32 -> 32
    hs1_kernel<<<(N * 32 + B - 1) / B, B, 0, stream>>>(x, W1, deg, bufA, N);
    scatter_kernel<32><<<(int)(((long long)E * 32 + B - 1) / B), B, 0, stream>>>(ei, bufA, bufB, E);
    finalize_kernel<32><<<(N * 32 + B - 1) / B, B, 0, stream>>>(bufA, bufB, deg, b1, bufB, N);

    // layer 2: 32 -> 24
    hs2_kernel<<<(N * 24 + B - 1) / B, B, 0, stream>>>(bufB, W2, deg, bufA, N);
    scatter_kernel<24><<<(int)(((long long)E * 24 + B - 1) / B), B, 0, stream>>>(ei, bufA, bufC, E);
    finalize_kernel<24><<<(N * 24 + B - 1) / B, B, 0, stream>>>(bufA, bufC, deg, b2, bufB, N);

    // node logits, per-graph fused epilogue, final column softmax
    nlogit_kernel<<<(N + B - 1) / B, B, 0, stream>>>(bufB, Wn1, bn1, Wn2, bn2, bufC, N);
    graph_kernel<<<NG, B, 0, stream>>>(bufC, bufB, bat, Wg, bg, Wt, bt,
                                       Wb1, bb1, Wb2, bb2, out_t, out_n, bbpre, N);
    bb_kernel<<<1, B, 0, stream>>>(bbpre, out_bb);
}

// Round 2
// 877.603 us; speedup vs baseline: 1.1898x; 1.1898x over previous
//
#include <hip/hip_runtime.h>
#include <math.h>

#define NG 256   // NUM_GRAPHS

// ---------------------------------------------------------------------------
// in-degree histogram over edge targets (int atomics)
__global__ void hist_kernel(const int* __restrict__ col, int* __restrict__ indeg, int E) {
    int e = blockIdx.x * blockDim.x + threadIdx.x;
    if (e < E) atomicAdd(&indeg[col[e]], 1);
}

// single-block exclusive scan: indeg[N] -> rowptr[N+1]
__global__ __launch_bounds__(1024) void scan_kernel(const int* __restrict__ indeg,
                                                    int* __restrict__ rowptr, int N) {
    __shared__ int part[1024];
    const int t = threadIdx.x;
    const int C = (N + 1023) >> 10;
    const int beg = t * C;
    const int end = min(beg + C, N);
    int s = 0;
    for (int i = beg; i < end; i++) s += indeg[i];
    part[t] = s;
    __syncthreads();
    for (int off = 1; off < 1024; off <<= 1) {
        int v = (t >= off) ? part[t - off] : 0;
        __syncthreads();
        part[t] += v;
        __syncthreads();
    }
    int run = part[t] - s;   // exclusive prefix of this chunk
    for (int i = beg; i < end; i++) { rowptr[i] = run; run += indeg[i]; }
    if (t == 1023) rowptr[N] = part[1023];
}

// dinv = rsqrt(indeg+1); cursor <- rowptr (cursor ALIASES indeg: read-then-write per index)
__global__ void prep_kernel(const int* __restrict__ rowptr, int* __restrict__ cursor_indeg,
                            float* __restrict__ dinv, int N) {
    int i = blockIdx.x * blockDim.x + threadIdx.x;
    if (i >= N) return;
    int d = cursor_indeg[i];
    cursor_indeg[i] = rowptr[i];
    dinv[i] = rsqrtf((float)d + 1.0f);
}

// adj[pos] = source, grouped by target via atomic cursors
__global__ void fill_kernel(const int* __restrict__ ei, int* __restrict__ cursor,
                            int* __restrict__ adj, int E) {
    int e = blockIdx.x * blockDim.x + threadIdx.x;
    if (e >= E) return;
    int r = ei[e];        // source
    int c = ei[E + e];    // target
    int pos = atomicAdd(&cursor[c], 1);
    adj[pos] = r;
}

// hs1[i][f] = (sum_k x[i][k] * W1[k][f]) * dinv[i]   (32 -> 32)
__global__ __launch_bounds__(256) void hs1_kernel(
        const float* __restrict__ x, const float* __restrict__ W,
        const float* __restrict__ dinv, float* __restrict__ hs, int N) {
    __shared__ float Ws[32 * 32];
    for (int t = threadIdx.x; t < 1024; t += blockDim.x) Ws[t] = W[t];
    __syncthreads();
    int gid = blockIdx.x * blockDim.x + threadIdx.x;
    if (gid >= N * 32) return;
    int i = gid >> 5, f = gid & 31;
    const float* xr = x + (size_t)i * 32;
    float acc = 0.f;
#pragma unroll
    for (int k = 0; k < 32; k++) acc += xr[k] * Ws[k * 32 + f];
    hs[gid] = acc * dinv[i];
}

// ---------------------------------------------------------------------------
// gather layer 1 (F=32) with fused finalize AND fused hs2 staging:
//   h1 = relu(dinv*(gather(hs1) + hs1) + b1)          (kept only in LDS)
//   hs2[i][fo] = dinv[i] * sum_k h1[i][k] * W2[k][fo] (fo < 24)
__global__ __launch_bounds__(256) void gather1_kernel(
        const int* __restrict__ rowptr, const int* __restrict__ adj,
        const float* __restrict__ hs1, const float* __restrict__ dinv,
        const float* __restrict__ b1, const float* __restrict__ W2,
        float* __restrict__ hs2out, int N) {
    __shared__ float W2s[32 * 24];
    __shared__ float b1s[32];
    __shared__ float h1row[8][32];
    const int tid = threadIdx.x;
    for (int t = tid; t < 768; t += 256) W2s[t] = W2[t];
    if (tid < 32) b1s[tid] = b1[tid];

    const int node = blockIdx.x * 8 + (tid >> 5);
    const int f = tid & 31;
    const int n = tid >> 5;
    const bool valid = node < N;

    int beg = 0, cnt = 0;
    if (valid) { beg = rowptr[node]; cnt = rowptr[node + 1] - beg; }
    const int* ap = adj + beg;
    float acc = 0.f;
    int j = 0;
    for (; j + 4 <= cnt; j += 4) {
        int r0 = ap[j], r1 = ap[j + 1], r2 = ap[j + 2], r3 = ap[j + 3];
        acc += hs1[(size_t)r0 * 32 + f];
        acc += hs1[(size_t)r1 * 32 + f];
        acc += hs1[(size_t)r2 * 32 + f];
        acc += hs1[(size_t)r3 * 32 + f];
    }
    for (; j < cnt; j++) acc += hs1[(size_t)ap[j] * 32 + f];

    __syncthreads();   // weight-staging visibility (all threads reached here)

    float di = 0.f, h1v = 0.f;
    if (valid) {
        di = dinv[node];
        h1v = fmaxf(di * (acc + hs1[(size_t)node * 32 + f]) + b1s[f], 0.f);
    }
    h1row[n][f] = h1v;   // same-wave producer/consumer: no barrier needed

    if (valid && f < 24) {
        float a = 0.f;
#pragma unroll
        for (int k = 0; k < 32; k++) a += h1row[n][k] * W2s[k * 24 + f];
        hs2out[(size_t)node * 24 + f] = a * di;
    }
}

// gather layer 2 (F=24, padded to 32 lanes) with fused finalize AND fused node-MLP:
//   h2 = relu(dinv*(gather(hs2) + hs2) + b2)
//   v  = relu(h2 @ Wn1 + bn1) @ Wn2 + bn2
__global__ __launch_bounds__(256) void gather2_kernel(
        const int* __restrict__ rowptr, const int* __restrict__ adj,
        const float* __restrict__ hs2, const float* __restrict__ dinv,
        const float* __restrict__ b2,
        const float* __restrict__ Wn1, const float* __restrict__ bn1,
        const float* __restrict__ Wn2, const float* __restrict__ bn2,
        float* __restrict__ h2out, float* __restrict__ vout, int N) {
    __shared__ float Wn1s[24 * 16];
    __shared__ float b2s[24], bn1s[16], Wn2s[16];
    __shared__ float h2row[8][32];
    const int tid = threadIdx.x;
    for (int t = tid; t < 384; t += 256) Wn1s[t] = Wn1[t];
    if (tid < 24) b2s[tid] = b2[tid];
    if (tid < 16) { bn1s[tid] = bn1[tid]; Wn2s[tid] = Wn2[tid]; }

    const int node = blockIdx.x * 8 + (tid >> 5);
    const int f = tid & 31;
    const int n = tid >> 5;
    const bool valid = node < N;
    const bool fa = f < 24;

    int beg = 0, cnt = 0;
    if (valid && fa) { beg = rowptr[node]; cnt = rowptr[node + 1] - beg; }
    const int* ap = adj + beg;
    float acc = 0.f;
    int j = 0;
    for (; j + 4 <= cnt; j += 4) {
        int r0 = ap[j], r1 = ap[j + 1], r2 = ap[j + 2], r3 = ap[j + 3];
        acc += hs2[(size_t)r0 * 24 + f];
        acc += hs2[(size_t)r1 * 24 + f];
        acc += hs2[(size_t)r2 * 24 + f];
        acc += hs2[(size_t)r3 * 24 + f];
    }
    for (; j < cnt; j++) acc += hs2[(size_t)ap[j] * 24 + f];

    __syncthreads();   // weight-staging visibility

    float h2v = 0.f;
    if (valid && fa) {
        float di = dinv[node];
        h2v = fmaxf(di * (acc + hs2[(size_t)node * 24 + f]) + b2s[f], 0.f);
        h2out[(size_t)node * 24 + f] = h2v;
    }
    h2row[n][f] = fa ? h2v : 0.f;  // same-wave producer/consumer

    float val = 0.f;
    if (valid && f < 16) {
        float u = bn1s[f];
#pragma unroll
        for (int k = 0; k < 24; k++) u += h2row[n][k] * Wn1s[k * 16 + f];
        val = fmaxf(u, 0.f) * Wn2s[f];
    }
    val += __shfl_down(val, 8, 16);
    val += __shfl_down(val, 4, 16);
    val += __shfl_down(val, 2, 16);
    val += __shfl_down(val, 1, 16);
    if (valid && f == 0) vout[node] = val + bn2[0];
}

__device__ __forceinline__ int lower_bound_i(const int* __restrict__ a, int n, int key) {
    int lo = 0, hi = n;
    while (lo < hi) {
        int mid = (lo + hi) >> 1;
        if (a[mid] < key) lo = mid + 1; else hi = mid;
    }
    return lo;
}

// One block per graph (batch is sorted): segment softmax over nodes, mean pool,
// weighted pool, t-head, b-head pre-softmax. No global atomics.
__global__ __launch_bounds__(256) void graph_kernel(
        const float* __restrict__ v, const float* __restrict__ h2,
        const int* __restrict__ batch,
        const float* __restrict__ Wg, const float* __restrict__ bg,
        const float* __restrict__ Wt, const float* __restrict__ bt,
        const float* __restrict__ Wb1p, const float* __restrict__ bb1p,
        const float* __restrict__ Wb2p, const float* __restrict__ bb2p,
        float* __restrict__ out_t, float* __restrict__ out_n,
        float* __restrict__ bbpre, int N) {
    const int g = blockIdx.x;
    const int tid = threadIdx.x;
    const int lane = tid & 63;
    const int wid = tid >> 6;

    const int start = lower_bound_i(batch, N, g);
    const int end = lower_bound_i(batch, N, g + 1);

    __shared__ float sm[4];
    __shared__ float part[4][49];

    // pass A: max of v over the segment
    float m = -INFINITY;
    for (int idx = start + tid; idx < end; idx += 256) m = fmaxf(m, v[idx]);
#pragma unroll
    for (int off = 32; off > 0; off >>= 1) m = fmaxf(m, __shfl_down(m, off, 64));
    if (lane == 0) sm[wid] = m;
    __syncthreads();
    m = fmaxf(fmaxf(sm[0], sm[1]), fmaxf(sm[2], sm[3]));

    // pass B: s = sum exp(v-m); hsum = sum h2; wsum = sum exp(v-m)*h2
    float s = 0.f;
    float hsum[24], wsum[24];
#pragma unroll
    for (int f = 0; f < 24; f++) { hsum[f] = 0.f; wsum[f] = 0.f; }
    for (int idx = start + tid; idx < end; idx += 256) {
        float e = __expf(v[idx] - m);
        s += e;
        const float4* hr = (const float4*)(h2 + (size_t)idx * 24);
#pragma unroll
        for (int q = 0; q < 6; q++) {
            float4 x4 = hr[q];
            hsum[4 * q] += x4.x;  wsum[4 * q] += e * x4.x;
            hsum[4 * q + 1] += x4.y; wsum[4 * q + 1] += e * x4.y;
            hsum[4 * q + 2] += x4.z; wsum[4 * q + 2] += e * x4.z;
            hsum[4 * q + 3] += x4.w; wsum[4 * q + 3] += e * x4.w;
        }
    }
#pragma unroll
    for (int off = 32; off > 0; off >>= 1) {
        s += __shfl_down(s, off, 64);
#pragma unroll
        for (int f = 0; f < 24; f++) {
            hsum[f] += __shfl_down(hsum[f], off, 64);
            wsum[f] += __shfl_down(wsum[f], off, 64);
        }
    }
    if (lane == 0) {
        part[wid][0] = s;
#pragma unroll
        for (int f = 0; f < 24; f++) { part[wid][1 + f] = hsum[f]; part[wid][25 + f] = wsum[f]; }
    }
    __syncthreads();
    const float stot = part[0][0] + part[1][0] + part[2][0] + part[3][0];
    const float invs = (stot > 0.f) ? 1.f / stot : 0.f;

    // pass C: write normalized per-node softmax
    for (int idx = start + tid; idx < end; idx += 256)
        out_n[idx] = __expf(v[idx] - m) * invs;

    // graph-level heads on thread 0 (tiny)
    if (tid == 0) {
        float hsumT[24], wsumT[24];
#pragma unroll
        for (int f = 0; f < 24; f++) {
            hsumT[f] = part[0][1 + f] + part[1][1 + f] + part[2][1 + f] + part[3][1 + f];
            wsumT[f] = part[0][25 + f] + part[1][25 + f] + part[2][25 + f] + part[3][25 + f];
        }
        float cnt = (float)(end - start);
        float denom = fmaxf(cnt, 1.0f);

        float mean[24];
#pragma unroll
        for (int f = 0; f < 24; f++) mean[f] = hsumT[f] / denom;
        float gout[32];
        for (int o = 0; o < 32; o++) {
            float a = bg[o];
#pragma unroll
            for (int k = 0; k < 24; k++) a += mean[k] * Wg[k * 32 + o];
            gout[o] = a;
        }
        float t0 = bt[0], t1 = bt[1];
#pragma unroll
        for (int k = 0; k < 32; k++) { t0 += gout[k] * Wt[k * 2]; t1 += gout[k] * Wt[k * 2 + 1]; }
        float tm = fmaxf(t0, t1);
        float e0 = __expf(t0 - tm), e1 = __expf(t1 - tm);
        float ts = e0 + e1;
        out_t[g * 2 + 0] = e0 / ts;
        out_t[g * 2 + 1] = e1 / ts;

        float bf[24];
#pragma unroll
        for (int f = 0; f < 24; f++) bf[f] = wsumT[f] * invs;
        float u[16];
        for (int j = 0; j < 16; j++) {
            float a = bb1p[j];
#pragma unroll
            for (int k = 0; k < 24; k++) a += bf[k] * Wb1p[k * 16 + j];
            u[j] = fmaxf(a, 0.f);
        }
        for (int c = 0; c < 3; c++) {
            float a = bb2p[c];
#pragma unroll
            for (int j = 0; j < 16; j++) a += u[j] * Wb2p[j * 3 + c];
            bbpre[g * 3 + c] = a;
        }
    }
}

// column softmax over the 256 graphs (axis=0), 3 columns
__global__ __launch_bounds__(256) void bb_kernel(
        const float* __restrict__ bbpre, float* __restrict__ out_bb) {
    __shared__ float red[NG];
    int g = threadIdx.x;
#pragma unroll
    for (int c = 0; c < 3; c++) {
        float vv = bbpre[g * 3 + c];
        red[g] = vv;
        __syncthreads();
        for (int off = 128; off > 0; off >>= 1) {
            if (g < off) red[g] = fmaxf(red[g], red[g + off]);
            __syncthreads();
        }
        float m = red[0];
        __syncthreads();
        float e = __expf(vv - m);
        red[g] = e;
        __syncthreads();
        for (int off = 128; off > 0; off >>= 1) {
            if (g < off) red[g] += red[g + off];
            __syncthreads();
        }
        float ssum = red[0];
        __syncthreads();
        out_bb[g * 3 + c] = e / ssum;
    }
}

extern "C" void kernel_launch(void* const* d_in, const int* in_sizes, int n_in,
                              void* d_out, int out_size, void* d_ws, size_t ws_size,
                              hipStream_t stream) {
    const float* x   = (const float*)d_in[0];
    const int*   ei  = (const int*)d_in[1];    // [2,E] flat: row=ei[0..E), col=ei[E..2E)
    const int*   bat = (const int*)d_in[2];
    const float* W1  = (const float*)d_in[3];
    const float* b1  = (const float*)d_in[4];
    const float* W2  = (const float*)d_in[5];
    const float* b2  = (const float*)d_in[6];
    const float* Wg  = (const float*)d_in[7];
    const float* bg  = (const float*)d_in[8];
    const float* Wt  = (const float*)d_in[9];
    const float* bt  = (const float*)d_in[10];
    const float* Wn1 = (const float*)d_in[11];
    const float* bn1 = (const float*)d_in[12];
    const float* Wn2 = (const float*)d_in[13];
    const float* bn2 = (const float*)d_in[14];
    const float* Wb1 = (const float*)d_in[15];
    const float* bb1 = (const float*)d_in[16];
    const float* Wb2 = (const float*)d_in[17];
    const float* bb2 = (const float*)d_in[18];

    const int N = in_sizes[2];
    const int E = in_sizes[1] / 2;

    // workspace layout (4B elements), all offsets multiple of 4 for float4 use:
    // rowptr[N+1] | cursor/indeg[N] | dinv[N] | adj[E] | bufA[32N] | bufB[24N] | bbpre[768]
    auto rnd4 = [](size_t v) { return (v + 3) & ~(size_t)3; };
    size_t oRow = 0;
    size_t oCur = oRow + rnd4((size_t)N + 1);
    size_t oDin = oCur + rnd4((size_t)N);
    size_t oAdj = oDin + rnd4((size_t)N);
    size_t oA   = oAdj + rnd4((size_t)E);
    size_t oB   = oA + (size_t)32 * N;
    size_t oPre = oB + (size_t)24 * N;

    int*   wsi    = (int*)d_ws;
    float* wsf    = (float*)d_ws;
    int*   rowptr = wsi + oRow;
    int*   cursor = wsi + oCur;   // aliases indeg
    float* dinv   = wsf + oDin;
    int*   adj    = wsi + oAdj;
    float* bufA   = wsf + oA;     // hs1 (32N), later h2 (24N) + v (N)
    float* bufB   = wsf + oB;     // hs2 (24N)
    float* bbpre  = wsf + oPre;
    float* h2     = bufA;
    float* vbuf   = bufA + (size_t)24 * N;

    float* out_t  = (float*)d_out;          // [256,2]
    float* out_n  = out_t + 2 * NG;         // [N,1]
    float* out_bb = out_t + 2 * NG + N;     // [256,3]

    const int B = 256;
    hipMemsetAsync(cursor, 0, (size_t)N * sizeof(int), stream);  // indeg = 0

    hist_kernel<<<(E + B - 1) / B, B, 0, stream>>>(ei + E, cursor, E);
    scan_kernel<<<1, 1024, 0, stream>>>(cursor, rowptr, N);
    prep_kernel<<<(N + B - 1) / B, B, 0, stream>>>(rowptr, cursor, dinv, N);
    fill_kernel<<<(E + B - 1) / B, B, 0, stream>>>(ei, cursor, adj, E);

    hs1_kernel<<<(N * 32 + B - 1) / B, B, 0, stream>>>(x, W1, dinv, bufA, N);
    gather1_kernel<<<(N + 7) / 8, B, 0, stream>>>(rowptr, adj, bufA, dinv, b1, W2, bufB, N);
    gather2_kernel<<<(N + 7) / 8, B, 0, stream>>>(rowptr, adj, bufB, dinv, b2,
                                                  Wn1, bn1, Wn2, bn2, h2, vbuf, N);

    graph_kernel<<<NG, B, 0, stream>>>(vbuf, h2, bat, Wg, bg, Wt, bt,
                                       Wb1, bb1, Wb2, bb2, out_t, out_n, bbpre, N);
    bb_kernel<<<1, B, 0, stream>>>(bbpre, out_bb);
}

// Round 3
// 575.633 us; speedup vs baseline: 1.8140x; 1.5246x over previous
//
#include <hip/hip_runtime.h>
#include <math.h>

#define NG 256     // NUM_GRAPHS
#define NBLK 256   // blocks in histogram / pair-scatter passes
// bucket = target >> 8  (256 nodes per bucket); supports N <= 131072 (src packs in 17 bits)

// ---------------------------------------------------------------------------
// K1: per-block histogram of edge targets into NB buckets (LDS atomics only)
__global__ __launch_bounds__(256) void hist_bucket_kernel(
        const int* __restrict__ col, int* __restrict__ bh, int E, int NB) {
    __shared__ int h[512];
    for (int t = threadIdx.x; t < NB; t += 256) h[t] = 0;
    __syncthreads();
    const int chunk = (E + NBLK - 1) / NBLK;
    const int beg = blockIdx.x * chunk;
    const int end = min(beg + chunk, E);
    for (int e = beg + threadIdx.x; e < end; e += 256)
        atomicAdd(&h[col[e] >> 8], 1);
    __syncthreads();
    for (int t = threadIdx.x; t < NB; t += 256)
        bh[t * NBLK + blockIdx.x] = h[t];
}

// K2: exclusive scan of bh[NB*NBLK] (bucket-major) -> off; bucketBase[b] = off[b*NBLK]
__global__ __launch_bounds__(1024) void scan2_kernel(
        const int* __restrict__ bh, int* __restrict__ off,
        int* __restrict__ bucketBase, int M, int NB) {
    __shared__ int part[1024];
    const int t = threadIdx.x;
    const int C = (M + 1023) >> 10;
    const int beg = t * C;
    const int end = min(beg + C, M);
    int s = 0;
    for (int i = beg; i < end; i++) s += bh[i];
    part[t] = s;
    __syncthreads();
    for (int o = 1; o < 1024; o <<= 1) {
        int v = (t >= o) ? part[t - o] : 0;
        __syncthreads();
        part[t] += v;
        __syncthreads();
    }
    int run = part[t] - s;   // exclusive prefix of this chunk
    for (int i = beg; i < end; i++) {
        off[i] = run;
        if ((i & (NBLK - 1)) == 0) bucketBase[i >> 8] = run;   // NBLK == 256
        run += bh[i];
    }
    if (t == 1023) bucketBase[NB] = part[1023];   // total = E
}

// K3: scatter packed (local_tgt<<17 | src) pairs, grouped by bucket (LDS cursors)
__global__ __launch_bounds__(256) void scatter_pairs_kernel(
        const int* __restrict__ ei, const int* __restrict__ off,
        int* __restrict__ pairs, int E, int NB) {
    __shared__ int cur[512];
    for (int t = threadIdx.x; t < NB; t += 256) cur[t] = off[t * NBLK + blockIdx.x];
    __syncthreads();
    const int chunk = (E + NBLK - 1) / NBLK;
    const int beg = blockIdx.x * chunk;
    const int end = min(beg + chunk, E);
    for (int e = beg + threadIdx.x; e < end; e += 256) {
        int src = ei[e];
        int tgt = ei[E + e];
        int pos = atomicAdd(&cur[tgt >> 8], 1);
        pairs[pos] = (int)(((unsigned)(tgt & 255) << 17) | (unsigned)src);
    }
}

// K4: one block per bucket: local 256-bin histogram + scan -> rowptr, dinv, adj
__global__ __launch_bounds__(256) void csr_bucket_kernel(
        const int* __restrict__ pairs, const int* __restrict__ bucketBase,
        int* __restrict__ rowptr, int* __restrict__ adj,
        float* __restrict__ dinv, int N, int E) {
    __shared__ int h[256];
    __shared__ int sc[256];
    __shared__ int cur[256];
    const int b = blockIdx.x, t = threadIdx.x;
    const int base = bucketBase[b];
    const int end = bucketBase[b + 1];
    h[t] = 0;
    __syncthreads();
    for (int i = base + t; i < end; i += 256)
        atomicAdd(&h[(unsigned)pairs[i] >> 17], 1);
    __syncthreads();
    const int v = h[t];
    sc[t] = v;
    __syncthreads();
    for (int o = 1; o < 256; o <<= 1) {
        int u = (t >= o) ? sc[t - o] : 0;
        __syncthreads();
        sc[t] += u;
        __syncthreads();
    }
    const int ex = sc[t] - v;   // exclusive prefix within bucket
    const int node = (b << 8) + t;
    if (node < N) {
        rowptr[node] = base + ex;
        dinv[node] = rsqrtf((float)v + 1.0f);
    }
    cur[t] = base + ex;
    __syncthreads();
    for (int i = base + t; i < end; i += 256) {
        unsigned p = (unsigned)pairs[i];
        int pos = atomicAdd(&cur[p >> 17], 1);
        adj[pos] = (int)(p & 0x1FFFFu);
    }
    if (b == 0 && t == 0) rowptr[N] = E;
}

// ---------------------------------------------------------------------------
// hs1[i][f] = (sum_k x[i][k] * W1[k][f]) * dinv[i]   (32 -> 32)
__global__ __launch_bounds__(256) void hs1_kernel(
        const float* __restrict__ x, const float* __restrict__ W,
        const float* __restrict__ dinv, float* __restrict__ hs, int N) {
    __shared__ float Ws[32 * 32];
    for (int t = threadIdx.x; t < 1024; t += blockDim.x) Ws[t] = W[t];
    __syncthreads();
    int gid = blockIdx.x * blockDim.x + threadIdx.x;
    if (gid >= N * 32) return;
    int i = gid >> 5, f = gid & 31;
    const float* xr = x + (size_t)i * 32;
    float acc = 0.f;
#pragma unroll
    for (int k = 0; k < 32; k++) acc += xr[k] * Ws[k * 32 + f];
    hs[gid] = acc * dinv[i];
}

// gather layer 1 (F=32) with fused finalize AND fused hs2 staging:
//   h1 = relu(dinv*(gather(hs1) + hs1) + b1)          (kept only in LDS)
//   hs2[i][fo] = dinv[i] * sum_k h1[i][k] * W2[k][fo] (fo < 24)
__global__ __launch_bounds__(256) void gather1_kernel(
        const int* __restrict__ rowptr, const int* __restrict__ adj,
        const float* __restrict__ hs1, const float* __restrict__ dinv,
        const float* __restrict__ b1, const float* __restrict__ W2,
        float* __restrict__ hs2out, int N) {
    __shared__ float W2s[32 * 24];
    __shared__ float b1s[32];
    __shared__ float h1row[8][32];
    const int tid = threadIdx.x;
    for (int t = tid; t < 768; t += 256) W2s[t] = W2[t];
    if (tid < 32) b1s[tid] = b1[tid];

    const int node = blockIdx.x * 8 + (tid >> 5);
    const int f = tid & 31;
    const int n = tid >> 5;
    const bool valid = node < N;

    int beg = 0, cnt = 0;
    if (valid) { beg = rowptr[node]; cnt = rowptr[node + 1] - beg; }
    const int* ap = adj + beg;
    float acc = 0.f;
    int j = 0;
    for (; j + 4 <= cnt; j += 4) {
        int r0 = ap[j], r1 = ap[j + 1], r2 = ap[j + 2], r3 = ap[j + 3];
        acc += hs1[(size_t)r0 * 32 + f];
        acc += hs1[(size_t)r1 * 32 + f];
        acc += hs1[(size_t)r2 * 32 + f];
        acc += hs1[(size_t)r3 * 32 + f];
    }
    for (; j < cnt; j++) acc += hs1[(size_t)ap[j] * 32 + f];

    __syncthreads();   // weight-staging visibility (all threads reach here)

    float di = 0.f, h1v = 0.f;
    if (valid) {
        di = dinv[node];
        h1v = fmaxf(di * (acc + hs1[(size_t)node * 32 + f]) + b1s[f], 0.f);
    }
    h1row[n][f] = h1v;   // same-wave producer/consumer: no barrier needed

    if (valid && f < 24) {
        float a = 0.f;
#pragma unroll
        for (int k = 0; k < 32; k++) a += h1row[n][k] * W2s[k * 24 + f];
        hs2out[(size_t)node * 24 + f] = a * di;
    }
}

// gather layer 2 (F=24, padded to 32 lanes) with fused finalize AND fused node-MLP:
//   h2 = relu(dinv*(gather(hs2) + hs2) + b2)
//   v  = relu(h2 @ Wn1 + bn1) @ Wn2 + bn2
__global__ __launch_bounds__(256) void gather2_kernel(
        const int* __restrict__ rowptr, const int* __restrict__ adj,
        const float* __restrict__ hs2, const float* __restrict__ dinv,
        const float* __restrict__ b2,
        const float* __restrict__ Wn1, const float* __restrict__ bn1,
        const float* __restrict__ Wn2, const float* __restrict__ bn2,
        float* __restrict__ h2out, float* __restrict__ vout, int N) {
    __shared__ float Wn1s[24 * 16];
    __shared__ float b2s[24], bn1s[16], Wn2s[16];
    __shared__ float h2row[8][32];
    const int tid = threadIdx.x;
    for (int t = tid; t < 384; t += 256) Wn1s[t] = Wn1[t];
    if (tid < 24) b2s[tid] = b2[tid];
    if (tid < 16) { bn1s[tid] = bn1[tid]; Wn2s[tid] = Wn2[tid]; }

    const int node = blockIdx.x * 8 + (tid >> 5);
    const int f = tid & 31;
    const int n = tid >> 5;
    const bool valid = node < N;
    const bool fa = f < 24;

    int beg = 0, cnt = 0;
    if (valid && fa) { beg = rowptr[node]; cnt = rowptr[node + 1] - beg; }
    const int* ap = adj + beg;
    float acc = 0.f;
    int j = 0;
    for (; j + 4 <= cnt; j += 4) {
        int r0 = ap[j], r1 = ap[j + 1], r2 = ap[j + 2], r3 = ap[j + 3];
        acc += hs2[(size_t)r0 * 24 + f];
        acc += hs2[(size_t)r1 * 24 + f];
        acc += hs2[(size_t)r2 * 24 + f];
        acc += hs2[(size_t)r3 * 24 + f];
    }
    for (; j < cnt; j++) acc += hs2[(size_t)ap[j] * 24 + f];

    __syncthreads();   // weight-staging visibility

    float h2v = 0.f;
    if (valid && fa) {
        float di = dinv[node];
        h2v = fmaxf(di * (acc + hs2[(size_t)node * 24 + f]) + b2s[f], 0.f);
        h2out[(size_t)node * 24 + f] = h2v;
    }
    h2row[n][f] = fa ? h2v : 0.f;  // same-wave producer/consumer

    float val = 0.f;
    if (valid && f < 16) {
        float u = bn1s[f];
#pragma unroll
        for (int k = 0; k < 24; k++) u += h2row[n][k] * Wn1s[k * 16 + f];
        val = fmaxf(u, 0.f) * Wn2s[f];
    }
    val += __shfl_down(val, 8, 16);
    val += __shfl_down(val, 4, 16);
    val += __shfl_down(val, 2, 16);
    val += __shfl_down(val, 1, 16);
    if (valid && f == 0) vout[node] = val + bn2[0];
}

__device__ __forceinline__ int lower_bound_i(const int* __restrict__ a, int n, int key) {
    int lo = 0, hi = n;
    while (lo < hi) {
        int mid = (lo + hi) >> 1;
        if (a[mid] < key) lo = mid + 1; else hi = mid;
    }
    return lo;
}

// One block per graph (batch is sorted): segment softmax over nodes, mean pool,
// weighted pool, t-head, b-head pre-softmax. No global atomics.
__global__ __launch_bounds__(256) void graph_kernel(
        const float* __restrict__ v, const float* __restrict__ h2,
        const int* __restrict__ batch,
        const float* __restrict__ Wg, const float* __restrict__ bg,
        const float* __restrict__ Wt, const float* __restrict__ bt,
        const float* __restrict__ Wb1p, const float* __restrict__ bb1p,
        const float* __restrict__ Wb2p, const float* __restrict__ bb2p,
        float* __restrict__ out_t, float* __restrict__ out_n,
        float* __restrict__ bbpre, int N) {
    const int g = blockIdx.x;
    const int tid = threadIdx.x;
    const int lane = tid & 63;
    const int wid = tid >> 6;

    const int start = lower_bound_i(batch, N, g);
    const int end = lower_bound_i(batch, N, g + 1);

    __shared__ float sm[4];
    __shared__ float part[4][49];

    float m = -INFINITY;
    for (int idx = start + tid; idx < end; idx += 256) m = fmaxf(m, v[idx]);
#pragma unroll
    for (int off = 32; off > 0; off >>= 1) m = fmaxf(m, __shfl_down(m, off, 64));
    if (lane == 0) sm[wid] = m;
    __syncthreads();
    m = fmaxf(fmaxf(sm[0], sm[1]), fmaxf(sm[2], sm[3]));

    float s = 0.f;
    float hsum[24], wsum[24];
#pragma unroll
    for (int f = 0; f < 24; f++) { hsum[f] = 0.f; wsum[f] = 0.f; }
    for (int idx = start + tid; idx < end; idx += 256) {
        float e = __expf(v[idx] - m);
        s += e;
        const float4* hr = (const float4*)(h2 + (size_t)idx * 24);
#pragma unroll
        for (int q = 0; q < 6; q++) {
            float4 x4 = hr[q];
            hsum[4 * q] += x4.x;  wsum[4 * q] += e * x4.x;
            hsum[4 * q + 1] += x4.y; wsum[4 * q + 1] += e * x4.y;
            hsum[4 * q + 2] += x4.z; wsum[4 * q + 2] += e * x4.z;
            hsum[4 * q + 3] += x4.w; wsum[4 * q + 3] += e * x4.w;
        }
    }
#pragma unroll
    for (int off = 32; off > 0; off >>= 1) {
        s += __shfl_down(s, off, 64);
#pragma unroll
        for (int f = 0; f < 24; f++) {
            hsum[f] += __shfl_down(hsum[f], off, 64);
            wsum[f] += __shfl_down(wsum[f], off, 64);
        }
    }
    if (lane == 0) {
        part[wid][0] = s;
#pragma unroll
        for (int f = 0; f < 24; f++) { part[wid][1 + f] = hsum[f]; part[wid][25 + f] = wsum[f]; }
    }
    __syncthreads();
    const float stot = part[0][0] + part[1][0] + part[2][0] + part[3][0];
    const float invs = (stot > 0.f) ? 1.f / stot : 0.f;

    for (int idx = start + tid; idx < end; idx += 256)
        out_n[idx] = __expf(v[idx] - m) * invs;

    if (tid == 0) {
        float hsumT[24], wsumT[24];
#pragma unroll
        for (int f = 0; f < 24; f++) {
            hsumT[f] = part[0][1 + f] + part[1][1 + f] + part[2][1 + f] + part[3][1 + f];
            wsumT[f] = part[0][25 + f] + part[1][25 + f] + part[2][25 + f] + part[3][25 + f];
        }
        float cnt = (float)(end - start);
        float denom = fmaxf(cnt, 1.0f);

        float mean[24];
#pragma unroll
        for (int f = 0; f < 24; f++) mean[f] = hsumT[f] / denom;
        float gout[32];
        for (int o = 0; o < 32; o++) {
            float a = bg[o];
#pragma unroll
            for (int k = 0; k < 24; k++) a += mean[k] * Wg[k * 32 + o];
            gout[o] = a;
        }
        float t0 = bt[0], t1 = bt[1];
#pragma unroll
        for (int k = 0; k < 32; k++) { t0 += gout[k] * Wt[k * 2]; t1 += gout[k] * Wt[k * 2 + 1]; }
        float tm = fmaxf(t0, t1);
        float e0 = __expf(t0 - tm), e1 = __expf(t1 - tm);
        float ts = e0 + e1;
        out_t[g * 2 + 0] = e0 / ts;
        out_t[g * 2 + 1] = e1 / ts;

        float bf[24];
#pragma unroll
        for (int f = 0; f < 24; f++) bf[f] = wsumT[f] * invs;
        float u[16];
        for (int j = 0; j < 16; j++) {
            float a = bb1p[j];
#pragma unroll
            for (int k = 0; k < 24; k++) a += bf[k] * Wb1p[k * 16 + j];
            u[j] = fmaxf(a, 0.f);
        }
        for (int c = 0; c < 3; c++) {
            float a = bb2p[c];
#pragma unroll
            for (int j = 0; j < 16; j++) a += u[j] * Wb2p[j * 3 + c];
            bbpre[g * 3 + c] = a;
        }
    }
}

// column softmax over the 256 graphs (axis=0), 3 columns
__global__ __launch_bounds__(256) void bb_kernel(
        const float* __restrict__ bbpre, float* __restrict__ out_bb) {
    __shared__ float red[NG];
    int g = threadIdx.x;
#pragma unroll
    for (int c = 0; c < 3; c++) {
        float vv = bbpre[g * 3 + c];
        red[g] = vv;
        __syncthreads();
        for (int off = 128; off > 0; off >>= 1) {
            if (g < off) red[g] = fmaxf(red[g], red[g + off]);
            __syncthreads();
        }
        float m = red[0];
        __syncthreads();
        float e = __expf(vv - m);
        red[g] = e;
        __syncthreads();
        for (int off = 128; off > 0; off >>= 1) {
            if (g < off) red[g] += red[g + off];
            __syncthreads();
        }
        float ssum = red[0];
        __syncthreads();
        out_bb[g * 3 + c] = e / ssum;
    }
}

extern "C" void kernel_launch(void* const* d_in, const int* in_sizes, int n_in,
                              void* d_out, int out_size, void* d_ws, size_t ws_size,
                              hipStream_t stream) {
    const float* x   = (const float*)d_in[0];
    const int*   ei  = (const int*)d_in[1];    // [2,E] flat: row=ei[0..E), col=ei[E..2E)
    const int*   bat = (const int*)d_in[2];
    const float* W1  = (const float*)d_in[3];
    const float* b1  = (const float*)d_in[4];
    const float* W2  = (const float*)d_in[5];
    const float* b2  = (const float*)d_in[6];
    const float* Wg  = (const float*)d_in[7];
    const float* bg  = (const float*)d_in[8];
    const float* Wt  = (const float*)d_in[9];
    const float* bt  = (const float*)d_in[10];
    const float* Wn1 = (const float*)d_in[11];
    const float* bn1 = (const float*)d_in[12];
    const float* Wn2 = (const float*)d_in[13];
    const float* bn2 = (const float*)d_in[14];
    const float* Wb1 = (const float*)d_in[15];
    const float* bb1 = (const float*)d_in[16];
    const float* Wb2 = (const float*)d_in[17];
    const float* bb2 = (const float*)d_in[18];

    const int N = in_sizes[2];
    const int E = in_sizes[1] / 2;
    const int NB = (N + 255) >> 8;       // buckets of 256 nodes
    const int M = NB * NBLK;             // bh/off matrix size

    // workspace layout (4B units):
    // persistent: rowptr[N+1] | dinv[N] | adj[E] | bucketBase[NB+1]
    // transient (aliased union):
    //   build:   bh[M] | off[M] | pairs[E]
    //   compute: bufA[32N] (hs1 -> h2[24N]+v[N]) | bufB[24N] | bbpre[768]
    auto rnd4 = [](size_t v) { return (v + 3) & ~(size_t)3; };
    size_t oRow = 0;
    size_t oDin = oRow + rnd4((size_t)N + 1);
    size_t oAdj = oDin + rnd4((size_t)N);
    size_t oBB  = oAdj + rnd4((size_t)E);
    size_t oT   = oBB + rnd4((size_t)NB + 1);
    size_t oOff = oT + rnd4((size_t)M);
    size_t oPar = oOff + rnd4((size_t)M);

    int*   wsi     = (int*)d_ws;
    float* wsf     = (float*)d_ws;
    int*   rowptr  = wsi + oRow;
    float* dinv    = wsf + oDin;
    int*   adj     = wsi + oAdj;
    int*   bbase   = wsi + oBB;
    int*   bh      = wsi + oT;
    int*   offm    = wsi + oOff;
    int*   pairs   = wsi + oPar;
    float* bufA    = wsf + oT;            // hs1 (32N); later h2 (24N) + v (N)
    float* bufB    = wsf + oT + (size_t)32 * N;   // hs2 (24N)
    float* bbpre   = wsf + oT + (size_t)56 * N;
    float* h2      = bufA;
    float* vbuf    = bufA + (size_t)24 * N;

    float* out_t  = (float*)d_out;          // [256,2]
    float* out_n  = out_t + 2 * NG;         // [N,1]
    float* out_bb = out_t + 2 * NG + N;     // [256,3]

    const int B = 256;

    // CSR build: bucketed counting sort, LDS atomics only, dense global writes
    hist_bucket_kernel<<<NBLK, B, 0, stream>>>(ei + E, bh, E, NB);
    scan2_kernel<<<1, 1024, 0, stream>>>(bh, offm, bbase, M, NB);
    scatter_pairs_kernel<<<NBLK, B, 0, stream>>>(ei, offm, pairs, E, NB);
    csr_bucket_kernel<<<NB, B, 0, stream>>>(pairs, bbase, rowptr, adj, dinv, N, E);

    // GCN + heads
    hs1_kernel<<<(N * 32 + B - 1) / B, B, 0, stream>>>(x, W1, dinv, bufA, N);
    gather1_kernel<<<(N + 7) / 8, B, 0, stream>>>(rowptr, adj, bufA, dinv, b1, W2, bufB, N);
    gather2_kernel<<<(N + 7) / 8, B, 0, stream>>>(rowptr, adj, bufB, dinv, b2,
                                                  Wn1, bn1, Wn2, bn2, h2, vbuf, N);
    graph_kernel<<<NG, B, 0, stream>>>(vbuf, h2, bat, Wg, bg, Wt, bt,
                                       Wb1, bb1, Wb2, bb2, out_t, out_n, bbpre, N);
    bb_kernel<<<1, B, 0, stream>>>(bbpre, out_bb);
}

// Round 4
// 426.127 us; speedup vs baseline: 2.4504x; 1.3508x over previous
//
#include <hip/hip_runtime.h>
#include <math.h>

#define NG 256     // NUM_GRAPHS
#define NBLK 256   // blocks in histogram / pair-scatter passes
// bucket = target >> 8  (256 nodes per bucket); supports N <= 131072 (src packs in 17 bits)

// ---------------------------------------------------------------------------
// K1: per-block histogram of edge targets into NB buckets (LDS atomics), then
// reserve this block's range in each bucket via one global atomic per bucket.
// blockOff[b*NBLK+blk] = offset of this block's edges within bucket b.
__global__ __launch_bounds__(256) void hist_bucket_kernel(
        const int* __restrict__ col, int* __restrict__ blockOff,
        int* __restrict__ bucketTot, int E, int NB) {
    __shared__ int h[512];
    for (int t = threadIdx.x; t < NB; t += 256) h[t] = 0;
    __syncthreads();
    const int chunk = (E + NBLK - 1) / NBLK;
    const int beg = blockIdx.x * chunk;
    const int end = min(beg + chunk, E);
    for (int e = beg + threadIdx.x; e < end; e += 256)
        atomicAdd(&h[col[e] >> 8], 1);
    __syncthreads();
    for (int t = threadIdx.x; t < NB; t += 256) {
        int off = atomicAdd(&bucketTot[t], h[t]);   // reserve range (order arbitrary)
        blockOff[t * NBLK + blockIdx.x] = off;
    }
}

// K2: tiny exclusive scan over bucketTot[NB] -> bucketBase[NB+1]  (NB <= 512)
__global__ __launch_bounds__(512) void tiny_scan_kernel(
        const int* __restrict__ bucketTot, int* __restrict__ bucketBase, int NB) {
    __shared__ int part[512];
    const int t = threadIdx.x;
    int v = (t < NB) ? bucketTot[t] : 0;
    part[t] = v;
    __syncthreads();
    for (int o = 1; o < 512; o <<= 1) {
        int u = (t >= o) ? part[t - o] : 0;
        __syncthreads();
        part[t] += u;
        __syncthreads();
    }
    if (t < NB) bucketBase[t] = part[t] - v;   // exclusive
    if (t == NB) bucketBase[NB] = part[NB - 1];
    if (t == 511 && NB == 512) bucketBase[NB] = part[511];
}

// K3: scatter packed (local_tgt<<17 | src) pairs, grouped by bucket (LDS cursors)
__global__ __launch_bounds__(256) void scatter_pairs_kernel(
        const int* __restrict__ ei, const int* __restrict__ blockOff,
        const int* __restrict__ bucketBase, int* __restrict__ pairs, int E, int NB) {
    __shared__ int cur[512];
    for (int t = threadIdx.x; t < NB; t += 256)
        cur[t] = bucketBase[t] + blockOff[t * NBLK + blockIdx.x];
    __syncthreads();
    const int chunk = (E + NBLK - 1) / NBLK;
    const int beg = blockIdx.x * chunk;
    const int end = min(beg + chunk, E);
    for (int e = beg + threadIdx.x; e < end; e += 256) {
        int src = ei[e];
        int tgt = ei[E + e];
        int pos = atomicAdd(&cur[tgt >> 8], 1);
        pairs[pos] = (int)(((unsigned)(tgt & 255) << 17) | (unsigned)src);
    }
}

// K4: one block per bucket: local 256-bin histogram + scan -> rowptr, dinv, adj
__global__ __launch_bounds__(256) void csr_bucket_kernel(
        const int* __restrict__ pairs, const int* __restrict__ bucketBase,
        int* __restrict__ rowptr, int* __restrict__ adj,
        float* __restrict__ dinv, int N, int E) {
    __shared__ int h[256];
    __shared__ int sc[256];
    __shared__ int cur[256];
    const int b = blockIdx.x, t = threadIdx.x;
    const int base = bucketBase[b];
    const int end = bucketBase[b + 1];
    h[t] = 0;
    __syncthreads();
    for (int i = base + t; i < end; i += 256)
        atomicAdd(&h[(unsigned)pairs[i] >> 17], 1);
    __syncthreads();
    const int v = h[t];
    sc[t] = v;
    __syncthreads();
    for (int o = 1; o < 256; o <<= 1) {
        int u = (t >= o) ? sc[t - o] : 0;
        __syncthreads();
        sc[t] += u;
        __syncthreads();
    }
    const int ex = sc[t] - v;   // exclusive prefix within bucket
    const int node = (b << 8) + t;
    if (node < N) {
        rowptr[node] = base + ex;
        dinv[node] = rsqrtf((float)v + 1.0f);
    }
    cur[t] = base + ex;
    __syncthreads();
    for (int i = base + t; i < end; i += 256) {
        unsigned p = (unsigned)pairs[i];
        int pos = atomicAdd(&cur[p >> 17], 1);
        adj[pos] = (int)(p & 0x1FFFFu);
    }
    if (b == 0 && t == 0) rowptr[N] = E;
}

// ---------------------------------------------------------------------------
// hs1[i][f] = (sum_k x[i][k] * W1[k][f]) * dinv[i]   (32 -> 32)
__global__ __launch_bounds__(256) void hs1_kernel(
        const float* __restrict__ x, const float* __restrict__ W,
        const float* __restrict__ dinv, float* __restrict__ hs, int N) {
    __shared__ float Ws[32 * 32];
    for (int t = threadIdx.x; t < 1024; t += blockDim.x) Ws[t] = W[t];
    __syncthreads();
    int gid = blockIdx.x * blockDim.x + threadIdx.x;
    if (gid >= N * 32) return;
    int i = gid >> 5, f = gid & 31;
    const float* xr = x + (size_t)i * 32;
    float acc = 0.f;
#pragma unroll
    for (int k = 0; k < 32; k++) acc += xr[k] * Ws[k * 32 + f];
    hs[gid] = acc * dinv[i];
}

// gather layer 1 (F=32) with fused finalize AND fused hs2 staging:
//   h1 = relu(dinv*(gather(hs1) + hs1) + b1)          (kept only in LDS)
//   hs2[i][fo] = dinv[i] * sum_k h1[i][k] * W2[k][fo] (fo < 24)
__global__ __launch_bounds__(256) void gather1_kernel(
        const int* __restrict__ rowptr, const int* __restrict__ adj,
        const float* __restrict__ hs1, const float* __restrict__ dinv,
        const float* __restrict__ b1, const float* __restrict__ W2,
        float* __restrict__ hs2out, int N) {
    __shared__ float W2s[32 * 24];
    __shared__ float b1s[32];
    __shared__ float h1row[8][32];
    const int tid = threadIdx.x;
    for (int t = tid; t < 768; t += 256) W2s[t] = W2[t];
    if (tid < 32) b1s[tid] = b1[tid];

    const int node = blockIdx.x * 8 + (tid >> 5);
    const int f = tid & 31;
    const int n = tid >> 5;
    const bool valid = node < N;

    int beg = 0, cnt = 0;
    if (valid) { beg = rowptr[node]; cnt = rowptr[node + 1] - beg; }
    const int* ap = adj + beg;
    float acc = 0.f;
    int j = 0;
    for (; j + 4 <= cnt; j += 4) {
        int r0 = ap[j], r1 = ap[j + 1], r2 = ap[j + 2], r3 = ap[j + 3];
        acc += hs1[(size_t)r0 * 32 + f];
        acc += hs1[(size_t)r1 * 32 + f];
        acc += hs1[(size_t)r2 * 32 + f];
        acc += hs1[(size_t)r3 * 32 + f];
    }
    for (; j < cnt; j++) acc += hs1[(size_t)ap[j] * 32 + f];

    __syncthreads();   // weight-staging visibility (all threads reach here)

    float di = 0.f, h1v = 0.f;
    if (valid) {
        di = dinv[node];
        h1v = fmaxf(di * (acc + hs1[(size_t)node * 32 + f]) + b1s[f], 0.f);
    }
    h1row[n][f] = h1v;   // same-wave producer/consumer: no barrier needed

    if (valid && f < 24) {
        float a = 0.f;
#pragma unroll
        for (int k = 0; k < 32; k++) a += h1row[n][k] * W2s[k * 24 + f];
        hs2out[(size_t)node * 24 + f] = a * di;
    }
}

// gather layer 2 (F=24, padded to 32 lanes) with fused finalize AND fused node-MLP:
//   h2 = relu(dinv*(gather(hs2) + hs2) + b2)
//   v  = relu(h2 @ Wn1 + bn1) @ Wn2 + bn2
__global__ __launch_bounds__(256) void gather2_kernel(
        const int* __restrict__ rowptr, const int* __restrict__ adj,
        const float* __restrict__ hs2, const float* __restrict__ dinv,
        const float* __restrict__ b2,
        const float* __restrict__ Wn1, const float* __restrict__ bn1,
        const float* __restrict__ Wn2, const float* __restrict__ bn2,
        float* __restrict__ h2out, float* __restrict__ vout, int N) {
    __shared__ float Wn1s[24 * 16];
    __shared__ float b2s[24], bn1s[16], Wn2s[16];
    __shared__ float h2row[8][32];
    const int tid = threadIdx.x;
    for (int t = tid; t < 384; t += 256) Wn1s[t] = Wn1[t];
    if (tid < 24) b2s[tid] = b2[tid];
    if (tid < 16) { bn1s[tid] = bn1[tid]; Wn2s[tid] = Wn2[tid]; }

    const int node = blockIdx.x * 8 + (tid >> 5);
    const int f = tid & 31;
    const int n = tid >> 5;
    const bool valid = node < N;
    const bool fa = f < 24;

    int beg = 0, cnt = 0;
    if (valid && fa) { beg = rowptr[node]; cnt = rowptr[node + 1] - beg; }
    const int* ap = adj + beg;
    float acc = 0.f;
    int j = 0;
    for (; j + 4 <= cnt; j += 4) {
        int r0 = ap[j], r1 = ap[j + 1], r2 = ap[j + 2], r3 = ap[j + 3];
        acc += hs2[(size_t)r0 * 24 + f];
        acc += hs2[(size_t)r1 * 24 + f];
        acc += hs2[(size_t)r2 * 24 + f];
        acc += hs2[(size_t)r3 * 24 + f];
    }
    for (; j < cnt; j++) acc += hs2[(size_t)ap[j] * 24 + f];

    __syncthreads();   // weight-staging visibility

    float h2v = 0.f;
    if (valid && fa) {
        float di = dinv[node];
        h2v = fmaxf(di * (acc + hs2[(size_t)node * 24 + f]) + b2s[f], 0.f);
        h2out[(size_t)node * 24 + f] = h2v;
    }
    h2row[n][f] = fa ? h2v : 0.f;  // same-wave producer/consumer

    float val = 0.f;
    if (valid && f < 16) {
        float u = bn1s[f];
#pragma unroll
        for (int k = 0; k < 24; k++) u += h2row[n][k] * Wn1s[k * 16 + f];
        val = fmaxf(u, 0.f) * Wn2s[f];
    }
    val += __shfl_down(val, 8, 16);
    val += __shfl_down(val, 4, 16);
    val += __shfl_down(val, 2, 16);
    val += __shfl_down(val, 1, 16);
    if (valid && f == 0) vout[node] = val + bn2[0];
}

__device__ __forceinline__ int lower_bound_i(const int* __restrict__ a, int n, int key) {
    int lo = 0, hi = n;
    while (lo < hi) {
        int mid = (lo + hi) >> 1;
        if (a[mid] < key) lo = mid + 1; else hi = mid;
    }
    return lo;
}

// One block per graph (batch is sorted): segment softmax over nodes, mean pool,
// weighted pool, t-head, b-head pre-softmax. No global atomics.
__global__ __launch_bounds__(256) void graph_kernel(
        const float* __restrict__ v, const float* __restrict__ h2,
        const int* __restrict__ batch,
        const float* __restrict__ Wg, const float* __restrict__ bg,
        const float* __restrict__ Wt, const float* __restrict__ bt,
        const float* __restrict__ Wb1p, const float* __restrict__ bb1p,
        const float* __restrict__ Wb2p, const float* __restrict__ bb2p,
        float* __restrict__ out_t, float* __restrict__ out_n,
        float* __restrict__ bbpre, int N) {
    const int g = blockIdx.x;
    const int tid = threadIdx.x;
    const int lane = tid & 63;
    const int wid = tid >> 6;

    const int start = lower_bound_i(batch, N, g);
    const int end = lower_bound_i(batch, N, g + 1);

    __shared__ float sm[4];
    __shared__ float part[4][49];

    float m = -INFINITY;
    for (int idx = start + tid; idx < end; idx += 256) m = fmaxf(m, v[idx]);
#pragma unroll
    for (int off = 32; off > 0; off >>= 1) m = fmaxf(m, __shfl_down(m, off, 64));
    if (lane == 0) sm[wid] = m;
    __syncthreads();
    m = fmaxf(fmaxf(sm[0], sm[1]), fmaxf(sm[2], sm[3]));

    float s = 0.f;
    float hsum[24], wsum[24];
#pragma unroll
    for (int f = 0; f < 24; f++) { hsum[f] = 0.f; wsum[f] = 0.f; }
    for (int idx = start + tid; idx < end; idx += 256) {
        float e = __expf(v[idx] - m);
        s += e;
        const float4* hr = (const float4*)(h2 + (size_t)idx * 24);
#pragma unroll
        for (int q = 0; q < 6; q++) {
            float4 x4 = hr[q];
            hsum[4 * q] += x4.x;  wsum[4 * q] += e * x4.x;
            hsum[4 * q + 1] += x4.y; wsum[4 * q + 1] += e * x4.y;
            hsum[4 * q + 2] += x4.z; wsum[4 * q + 2] += e * x4.z;
            hsum[4 * q + 3] += x4.w; wsum[4 * q + 3] += e * x4.w;
        }
    }
#pragma unroll
    for (int off = 32; off > 0; off >>= 1) {
        s += __shfl_down(s, off, 64);
#pragma unroll
        for (int f = 0; f < 24; f++) {
            hsum[f] += __shfl_down(hsum[f], off, 64);
            wsum[f] += __shfl_down(wsum[f], off, 64);
        }
    }
    if (lane == 0) {
        part[wid][0] = s;
#pragma unroll
        for (int f = 0; f < 24; f++) { part[wid][1 + f] = hsum[f]; part[wid][25 + f] = wsum[f]; }
    }
    __syncthreads();
    const float stot = part[0][0] + part[1][0] + part[2][0] + part[3][0];
    const float invs = (stot > 0.f) ? 1.f / stot : 0.f;

    for (int idx = start + tid; idx < end; idx += 256)
        out_n[idx] = __expf(v[idx] - m) * invs;

    if (tid == 0) {
        float hsumT[24], wsumT[24];
#pragma unroll
        for (int f = 0; f < 24; f++) {
            hsumT[f] = part[0][1 + f] + part[1][1 + f] + part[2][1 + f] + part[3][1 + f];
            wsumT[f] = part[0][25 + f] + part[1][25 + f] + part[2][25 + f] + part[3][25 + f];
        }
        float cnt = (float)(end - start);
        float denom = fmaxf(cnt, 1.0f);

        float mean[24];
#pragma unroll
        for (int f = 0; f < 24; f++) mean[f] = hsumT[f] / denom;
        float gout[32];
        for (int o = 0; o < 32; o++) {
            float a = bg[o];
#pragma unroll
            for (int k = 0; k < 24; k++) a += mean[k] * Wg[k * 32 + o];
            gout[o] = a;
        }
        float t0 = bt[0], t1 = bt[1];
#pragma unroll
        for (int k = 0; k < 32; k++) { t0 += gout[k] * Wt[k * 2]; t1 += gout[k] * Wt[k * 2 + 1]; }
        float tm = fmaxf(t0, t1);
        float e0 = __expf(t0 - tm), e1 = __expf(t1 - tm);
        float ts = e0 + e1;
        out_t[g * 2 + 0] = e0 / ts;
        out_t[g * 2 + 1] = e1 / ts;

        float bf[24];
#pragma unroll
        for (int f = 0; f < 24; f++) bf[f] = wsumT[f] * invs;
        float u[16];
        for (int j = 0; j < 16; j++) {
            float a = bb1p[j];
#pragma unroll
            for (int k = 0; k < 24; k++) a += bf[k] * Wb1p[k * 16 + j];
            u[j] = fmaxf(a, 0.f);
        }
        for (int c = 0; c < 3; c++) {
            float a = bb2p[c];
#pragma unroll
            for (int j = 0; j < 16; j++) a += u[j] * Wb2p[j * 3 + c];
            bbpre[g * 3 + c] = a;
        }
    }
}

// column softmax over the 256 graphs (axis=0), 3 columns
__global__ __launch_bounds__(256) void bb_kernel(
        const float* __restrict__ bbpre, float* __restrict__ out_bb) {
    __shared__ float red[NG];
    int g = threadIdx.x;
#pragma unroll
    for (int c = 0; c < 3; c++) {
        float vv = bbpre[g * 3 + c];
        red[g] = vv;
        __syncthreads();
        for (int off = 128; off > 0; off >>= 1) {
            if (g < off) red[g] = fmaxf(red[g], red[g + off]);
            __syncthreads();
        }
        float m = red[0];
        __syncthreads();
        float e = __expf(vv - m);
        red[g] = e;
        __syncthreads();
        for (int off = 128; off > 0; off >>= 1) {
            if (g < off) red[g] += red[g + off];
            __syncthreads();
        }
        float ssum = red[0];
        __syncthreads();
        out_bb[g * 3 + c] = e / ssum;
    }
}

extern "C" void kernel_launch(void* const* d_in, const int* in_sizes, int n_in,
                              void* d_out, int out_size, void* d_ws, size_t ws_size,
                              hipStream_t stream) {
    const float* x   = (const float*)d_in[0];
    const int*   ei  = (const int*)d_in[1];    // [2,E] flat: row=ei[0..E), col=ei[E..2E)
    const int*   bat = (const int*)d_in[2];
    const float* W1  = (const float*)d_in[3];
    const float* b1  = (const float*)d_in[4];
    const float* W2  = (const float*)d_in[5];
    const float* b2  = (const float*)d_in[6];
    const float* Wg  = (const float*)d_in[7];
    const float* bg  = (const float*)d_in[8];
    const float* Wt  = (const float*)d_in[9];
    const float* bt  = (const float*)d_in[10];
    const float* Wn1 = (const float*)d_in[11];
    const float* bn1 = (const float*)d_in[12];
    const float* Wn2 = (const float*)d_in[13];
    const float* bn2 = (const float*)d_in[14];
    const float* Wb1 = (const float*)d_in[15];
    const float* bb1 = (const float*)d_in[16];
    const float* Wb2 = (const float*)d_in[17];
    const float* bb2 = (const float*)d_in[18];

    const int N = in_sizes[2];
    const int E = in_sizes[1] / 2;
    const int NB = (N + 255) >> 8;       // buckets of 256 nodes
    const int M = NB * NBLK;             // blockOff matrix size

    // workspace layout (4B units):
    // persistent: rowptr[N+1] | dinv[N] | adj[E] | bucketBase[NB+1] | bucketTot[NB]
    // transient (aliased union):
    //   build:   blockOff[M] | pairs[E]
    //   compute: bufA[32N] (hs1 -> h2[24N]+v[N]) | bufB[24N] | bbpre[768]
    auto rnd4 = [](size_t v) { return (v + 3) & ~(size_t)3; };
    size_t oRow = 0;
    size_t oDin = oRow + rnd4((size_t)N + 1);
    size_t oAdj = oDin + rnd4((size_t)N);
    size_t oBB  = oAdj + rnd4((size_t)E);
    size_t oTot = oBB + rnd4((size_t)NB + 1);
    size_t oT   = oTot + rnd4((size_t)NB);
    size_t oPar = oT + rnd4((size_t)M);

    int*   wsi     = (int*)d_ws;
    float* wsf     = (float*)d_ws;
    int*   rowptr  = wsi + oRow;
    float* dinv    = wsf + oDin;
    int*   adj     = wsi + oAdj;
    int*   bbase   = wsi + oBB;
    int*   btot    = wsi + oTot;
    int*   blkoff  = wsi + oT;
    int*   pairs   = wsi + oPar;
    float* bufA    = wsf + oT;                    // hs1 (32N); later h2 (24N) + v (N)
    float* bufB    = wsf + oT + (size_t)32 * N;   // hs2 (24N)
    float* bbpre   = wsf + oT + (size_t)56 * N;
    float* h2      = bufA;
    float* vbuf    = bufA + (size_t)24 * N;

    float* out_t  = (float*)d_out;          // [256,2]
    float* out_n  = out_t + 2 * NG;         // [N,1]
    float* out_bb = out_t + 2 * NG + N;     // [256,3]

    const int B = 256;

    // CSR build: bucketed counting sort; only tiny NB-sized scan is serial
    hipMemsetAsync(btot, 0, (size_t)NB * sizeof(int), stream);
    hist_bucket_kernel<<<NBLK, B, 0, stream>>>(ei + E, blkoff, btot, E, NB);
    tiny_scan_kernel<<<1, 512, 0, stream>>>(btot, bbase, NB);
    scatter_pairs_kernel<<<NBLK, B, 0, stream>>>(ei, blkoff, bbase, pairs, E, NB);
    csr_bucket_kernel<<<NB, B, 0, stream>>>(pairs, bbase, rowptr, adj, dinv, N, E);

    // GCN + heads
    hs1_kernel<<<(N * 32 + B - 1) / B, B, 0, stream>>>(x, W1, dinv, bufA, N);
    gather1_kernel<<<(N + 7) / 8, B, 0, stream>>>(rowptr, adj, bufA, dinv, b1, W2, bufB, N);
    gather2_kernel<<<(N + 7) / 8, B, 0, stream>>>(rowptr, adj, bufB, dinv, b2,
                                                  Wn1, bn1, Wn2, bn2, h2, vbuf, N);
    graph_kernel<<<NG, B, 0, stream>>>(vbuf, h2, bat, Wg, bg, Wt, bt,
                                       Wb1, bb1, Wb2, bb2, out_t, out_n, bbpre, N);
    bb_kernel<<<1, B, 0, stream>>>(bbpre, out_bb);
}

// Round 5
// 382.048 us; speedup vs baseline: 2.7331x; 1.1154x over previous
//
#include <hip/hip_runtime.h>
#include <math.h>

#define NG 256     // NUM_GRAPHS
#define NBLK 256   // blocks in histogram / pair-scatter passes
// bucket = target >> 8  (256 nodes per bucket); supports N <= 131072 (src packs in 17 bits)

typedef unsigned short ushort_t;

__device__ __forceinline__ float bf2f(ushort_t u) {
    return __uint_as_float(((unsigned)u) << 16);
}
__device__ __forceinline__ ushort_t f2bf(float x) {   // round-to-nearest-even
    unsigned u = __float_as_uint(x);
    unsigned r = (u + 0x7FFFu + ((u >> 16) & 1u)) >> 16;
    return (ushort_t)r;
}

// ---------------------------------------------------------------------------
// K1: per-block histogram of edge targets into NB buckets (LDS atomics), then
// reserve this block's range in each bucket via one global atomic per bucket.
__global__ __launch_bounds__(256) void hist_bucket_kernel(
        const int* __restrict__ col, int* __restrict__ blockOff,
        int* __restrict__ bucketTot, int E, int NB) {
    __shared__ int h[512];
    for (int t = threadIdx.x; t < NB; t += 256) h[t] = 0;
    __syncthreads();
    const int chunk = (E + NBLK - 1) / NBLK;
    const int beg = blockIdx.x * chunk;
    const int end = min(beg + chunk, E);
    for (int e = beg + threadIdx.x; e < end; e += 256)
        atomicAdd(&h[col[e] >> 8], 1);
    __syncthreads();
    for (int t = threadIdx.x; t < NB; t += 256) {
        int off = atomicAdd(&bucketTot[t], h[t]);   // reserve range (order arbitrary)
        blockOff[t * NBLK + blockIdx.x] = off;
    }
}

// K2: tiny exclusive scan over bucketTot[NB] -> bucketBase[NB+1]  (NB <= 512)
__global__ __launch_bounds__(512) void tiny_scan_kernel(
        const int* __restrict__ bucketTot, int* __restrict__ bucketBase, int NB) {
    __shared__ int part[512];
    const int t = threadIdx.x;
    int v = (t < NB) ? bucketTot[t] : 0;
    part[t] = v;
    __syncthreads();
    for (int o = 1; o < 512; o <<= 1) {
        int u = (t >= o) ? part[t - o] : 0;
        __syncthreads();
        part[t] += u;
        __syncthreads();
    }
    if (t < NB) bucketBase[t] = part[t] - v;   // exclusive
    if (t == NB) bucketBase[NB] = part[NB - 1];
    if (t == 511 && NB == 512) bucketBase[NB] = part[511];
}

// K3: scatter packed (local_tgt<<17 | src) pairs, grouped by bucket (LDS cursors)
__global__ __launch_bounds__(256) void scatter_pairs_kernel(
        const int* __restrict__ ei, const int* __restrict__ blockOff,
        const int* __restrict__ bucketBase, int* __restrict__ pairs, int E, int NB) {
    __shared__ int cur[512];
    for (int t = threadIdx.x; t < NB; t += 256)
        cur[t] = bucketBase[t] + blockOff[t * NBLK + blockIdx.x];
    __syncthreads();
    const int chunk = (E + NBLK - 1) / NBLK;
    const int beg = blockIdx.x * chunk;
    const int end = min(beg + chunk, E);
    for (int e = beg + threadIdx.x; e < end; e += 256) {
        int src = ei[e];
        int tgt = ei[E + e];
        int pos = atomicAdd(&cur[tgt >> 8], 1);
        pairs[pos] = (int)(((unsigned)(tgt & 255) << 17) | (unsigned)src);
    }
}

// K4: one block per bucket: local 256-bin histogram + scan -> rowptr, dinv, adj
__global__ __launch_bounds__(256) void csr_bucket_kernel(
        const int* __restrict__ pairs, const int* __restrict__ bucketBase,
        int* __restrict__ rowptr, int* __restrict__ adj,
        float* __restrict__ dinv, int N, int E) {
    __shared__ int h[256];
    __shared__ int sc[256];
    __shared__ int cur[256];
    const int b = blockIdx.x, t = threadIdx.x;
    const int base = bucketBase[b];
    const int end = bucketBase[b + 1];
    h[t] = 0;
    __syncthreads();
    for (int i = base + t; i < end; i += 256)
        atomicAdd(&h[(unsigned)pairs[i] >> 17], 1);
    __syncthreads();
    const int v = h[t];
    sc[t] = v;
    __syncthreads();
    for (int o = 1; o < 256; o <<= 1) {
        int u = (t >= o) ? sc[t - o] : 0;
        __syncthreads();
        sc[t] += u;
        __syncthreads();
    }
    const int ex = sc[t] - v;   // exclusive prefix within bucket
    const int node = (b << 8) + t;
    if (node < N) {
        rowptr[node] = base + ex;
        dinv[node] = rsqrtf((float)v + 1.0f);
    }
    cur[t] = base + ex;
    __syncthreads();
    for (int i = base + t; i < end; i += 256) {
        unsigned p = (unsigned)pairs[i];
        int pos = atomicAdd(&cur[p >> 17], 1);
        adj[pos] = (int)(p & 0x1FFFFu);
    }
    if (b == 0 && t == 0) rowptr[N] = E;
}

// ---------------------------------------------------------------------------
// hs1[i][f] = bf16( (sum_k x[i][k] * W1[k][f]) * dinv[i] )   (32 -> 32)
__global__ __launch_bounds__(256) void hs1_kernel(
        const float* __restrict__ x, const float* __restrict__ W,
        const float* __restrict__ dinv, ushort_t* __restrict__ hs, int N) {
    __shared__ float Ws[32 * 32];
    for (int t = threadIdx.x; t < 1024; t += blockDim.x) Ws[t] = W[t];
    __syncthreads();
    int gid = blockIdx.x * blockDim.x + threadIdx.x;
    if (gid >= N * 32) return;
    int i = gid >> 5, f = gid & 31;
    const float* xr = x + (size_t)i * 32;
    float acc = 0.f;
#pragma unroll
    for (int k = 0; k < 32; k++) acc += xr[k] * Ws[k * 32 + f];
    hs[gid] = f2bf(acc * dinv[i]);
}

// gather layer 1 (F=32, bf16 rows) with fused finalize AND fused hs2 staging:
//   h1 = relu(dinv*(gather(hs1) + hs1_self) + b1)     (kept only in LDS, fp32)
//   hs2[i][fo] = bf16( dinv[i] * sum_k h1[i][k] * W2[k][fo] )  (fo < 24)
__global__ __launch_bounds__(256) void gather1_kernel(
        const int* __restrict__ rowptr, const int* __restrict__ adj,
        const ushort_t* __restrict__ hs1, const float* __restrict__ dinv,
        const float* __restrict__ b1, const float* __restrict__ W2,
        ushort_t* __restrict__ hs2out, int N) {
    __shared__ float W2s[32 * 24];
    __shared__ float b1s[32];
    __shared__ float h1row[8][32];
    const int tid = threadIdx.x;
    for (int t = tid; t < 768; t += 256) W2s[t] = W2[t];
    if (tid < 32) b1s[tid] = b1[tid];

    const int node = blockIdx.x * 8 + (tid >> 5);
    const int f = tid & 31;
    const int n = tid >> 5;
    const bool valid = node < N;

    int beg = 0, cnt = 0;
    if (valid) { beg = rowptr[node]; cnt = rowptr[node + 1] - beg; }
    const int* ap = adj + beg;
    float acc = 0.f;
    int j = 0;
    for (; j + 4 <= cnt; j += 4) {
        int r0 = ap[j], r1 = ap[j + 1], r2 = ap[j + 2], r3 = ap[j + 3];
        acc += bf2f(hs1[(size_t)r0 * 32 + f]);
        acc += bf2f(hs1[(size_t)r1 * 32 + f]);
        acc += bf2f(hs1[(size_t)r2 * 32 + f]);
        acc += bf2f(hs1[(size_t)r3 * 32 + f]);
    }
    for (; j < cnt; j++) acc += bf2f(hs1[(size_t)ap[j] * 32 + f]);

    __syncthreads();   // weight-staging visibility (all threads reach here)

    float di = 0.f, h1v = 0.f;
    if (valid) {
        di = dinv[node];
        h1v = fmaxf(di * (acc + bf2f(hs1[(size_t)node * 32 + f])) + b1s[f], 0.f);
    }
    h1row[n][f] = h1v;   // same-wave producer/consumer: no barrier needed

    if (valid && f < 24) {
        float a = 0.f;
#pragma unroll
        for (int k = 0; k < 32; k++) a += h1row[n][k] * W2s[k * 24 + f];
        hs2out[(size_t)node * 24 + f] = f2bf(a * di);
    }
}

// gather layer 2 (F=24 bf16 rows, padded to 32 lanes) + fused finalize + node-MLP:
//   h2 = relu(dinv*(gather(hs2) + hs2_self) + b2)   (fp32 out for graph_kernel)
//   v  = relu(h2 @ Wn1 + bn1) @ Wn2 + bn2
__global__ __launch_bounds__(256) void gather2_kernel(
        const int* __restrict__ rowptr, const int* __restrict__ adj,
        const ushort_t* __restrict__ hs2, const float* __restrict__ dinv,
        const float* __restrict__ b2,
        const float* __restrict__ Wn1, const float* __restrict__ bn1,
        const float* __restrict__ Wn2, const float* __restrict__ bn2,
        float* __restrict__ h2out, float* __restrict__ vout, int N) {
    __shared__ float Wn1s[24 * 16];
    __shared__ float b2s[24], bn1s[16], Wn2s[16];
    __shared__ float h2row[8][32];
    const int tid = threadIdx.x;
    for (int t = tid; t < 384; t += 256) Wn1s[t] = Wn1[t];
    if (tid < 24) b2s[tid] = b2[tid];
    if (tid < 16) { bn1s[tid] = bn1[tid]; Wn2s[tid] = Wn2[tid]; }

    const int node = blockIdx.x * 8 + (tid >> 5);
    const int f = tid & 31;
    const int n = tid >> 5;
    const bool valid = node < N;
    const bool fa = f < 24;

    int beg = 0, cnt = 0;
    if (valid && fa) { beg = rowptr[node]; cnt = rowptr[node + 1] - beg; }
    const int* ap = adj + beg;
    float acc = 0.f;
    int j = 0;
    for (; j + 4 <= cnt; j += 4) {
        int r0 = ap[j], r1 = ap[j + 1], r2 = ap[j + 2], r3 = ap[j + 3];
        acc += bf2f(hs2[(size_t)r0 * 24 + f]);
        acc += bf2f(hs2[(size_t)r1 * 24 + f]);
        acc += bf2f(hs2[(size_t)r2 * 24 + f]);
        acc += bf2f(hs2[(size_t)r3 * 24 + f]);
    }
    for (; j < cnt; j++) acc += bf2f(hs2[(size_t)ap[j] * 24 + f]);

    __syncthreads();   // weight-staging visibility

    float h2v = 0.f;
    if (valid && fa) {
        float di = dinv[node];
        h2v = fmaxf(di * (acc + bf2f(hs2[(size_t)node * 24 + f])) + b2s[f], 0.f);
        h2out[(size_t)node * 24 + f] = h2v;
    }
    h2row[n][f] = fa ? h2v : 0.f;  // same-wave producer/consumer

    float val = 0.f;
    if (valid && f < 16) {
        float u = bn1s[f];
#pragma unroll
        for (int k = 0; k < 24; k++) u += h2row[n][k] * Wn1s[k * 16 + f];
        val = fmaxf(u, 0.f) * Wn2s[f];
    }
    val += __shfl_down(val, 8, 16);
    val += __shfl_down(val, 4, 16);
    val += __shfl_down(val, 2, 16);
    val += __shfl_down(val, 1, 16);
    if (valid && f == 0) vout[node] = val + bn2[0];
}

__device__ __forceinline__ int lower_bound_i(const int* __restrict__ a, int n, int key) {
    int lo = 0, hi = n;
    while (lo < hi) {
        int mid = (lo + hi) >> 1;
        if (a[mid] < key) lo = mid + 1; else hi = mid;
    }
    return lo;
}

// One block per graph (batch is sorted): segment softmax over nodes, mean pool,
// weighted pool, t-head, b-head pre-softmax. No global atomics.
__global__ __launch_bounds__(256) void graph_kernel(
        const float* __restrict__ v, const float* __restrict__ h2,
        const int* __restrict__ batch,
        const float* __restrict__ Wg, const float* __restrict__ bg,
        const float* __restrict__ Wt, const float* __restrict__ bt,
        const float* __restrict__ Wb1p, const float* __restrict__ bb1p,
        const float* __restrict__ Wb2p, const float* __restrict__ bb2p,
        float* __restrict__ out_t, float* __restrict__ out_n,
        float* __restrict__ bbpre, int N) {
    const int g = blockIdx.x;
    const int tid = threadIdx.x;
    const int lane = tid & 63;
    const int wid = tid >> 6;

    const int start = lower_bound_i(batch, N, g);
    const int end = lower_bound_i(batch, N, g + 1);

    __shared__ float sm[4];
    __shared__ float part[4][49];

    float m = -INFINITY;
    for (int idx = start + tid; idx < end; idx += 256) m = fmaxf(m, v[idx]);
#pragma unroll
    for (int off = 32; off > 0; off >>= 1) m = fmaxf(m, __shfl_down(m, off, 64));
    if (lane == 0) sm[wid] = m;
    __syncthreads();
    m = fmaxf(fmaxf(sm[0], sm[1]), fmaxf(sm[2], sm[3]));

    float s = 0.f;
    float hsum[24], wsum[24];
#pragma unroll
    for (int f = 0; f < 24; f++) { hsum[f] = 0.f; wsum[f] = 0.f; }
    for (int idx = start + tid; idx < end; idx += 256) {
        float e = __expf(v[idx] - m);
        s += e;
        const float4* hr = (const float4*)(h2 + (size_t)idx * 24);
#pragma unroll
        for (int q = 0; q < 6; q++) {
            float4 x4 = hr[q];
            hsum[4 * q] += x4.x;  wsum[4 * q] += e * x4.x;
            hsum[4 * q + 1] += x4.y; wsum[4 * q + 1] += e * x4.y;
            hsum[4 * q + 2] += x4.z; wsum[4 * q + 2] += e * x4.z;
            hsum[4 * q + 3] += x4.w; wsum[4 * q + 3] += e * x4.w;
        }
    }
#pragma unroll
    for (int off = 32; off > 0; off >>= 1) {
        s += __shfl_down(s, off, 64);
#pragma unroll
        for (int f = 0; f < 24; f++) {
            hsum[f] += __shfl_down(hsum[f], off, 64);
            wsum[f] += __shfl_down(wsum[f], off, 64);
        }
    }
    if (lane == 0) {
        part[wid][0] = s;
#pragma unroll
        for (int f = 0; f < 24; f++) { part[wid][1 + f] = hsum[f]; part[wid][25 + f] = wsum[f]; }
    }
    __syncthreads();
    const float stot = part[0][0] + part[1][0] + part[2][0] + part[3][0];
    const float invs = (stot > 0.f) ? 1.f / stot : 0.f;

    for (int idx = start + tid; idx < end; idx += 256)
        out_n[idx] = __expf(v[idx] - m) * invs;

    if (tid == 0) {
        float hsumT[24], wsumT[24];
#pragma unroll
        for (int f = 0; f < 24; f++) {
            hsumT[f] = part[0][1 + f] + part[1][1 + f] + part[2][1 + f] + part[3][1 + f];
            wsumT[f] = part[0][25 + f] + part[1][25 + f] + part[2][25 + f] + part[3][25 + f];
        }
        float cnt = (float)(end - start);
        float denom = fmaxf(cnt, 1.0f);

        float mean[24];
#pragma unroll
        for (int f = 0; f < 24; f++) mean[f] = hsumT[f] / denom;
        float gout[32];
        for (int o = 0; o < 32; o++) {
            float a = bg[o];
#pragma unroll
            for (int k = 0; k < 24; k++) a += mean[k] * Wg[k * 32 + o];
            gout[o] = a;
        }
        float t0 = bt[0], t1 = bt[1];
#pragma unroll
        for (int k = 0; k < 32; k++) { t0 += gout[k] * Wt[k * 2]; t1 += gout[k] * Wt[k * 2 + 1]; }
        float tm = fmaxf(t0, t1);
        float e0 = __expf(t0 - tm), e1 = __expf(t1 - tm);
        float ts = e0 + e1;
        out_t[g * 2 + 0] = e0 / ts;
        out_t[g * 2 + 1] = e1 / ts;

        float bf[24];
#pragma unroll
        for (int f = 0; f < 24; f++) bf[f] = wsumT[f] * invs;
        float u[16];
        for (int j = 0; j < 16; j++) {
            float a = bb1p[j];
#pragma unroll
            for (int k = 0; k < 24; k++) a += bf[k] * Wb1p[k * 16 + j];
            u[j] = fmaxf(a, 0.f);
        }
        for (int c = 0; c < 3; c++) {
            float a = bb2p[c];
#pragma unroll
            for (int j = 0; j < 16; j++) a += u[j] * Wb2p[j * 3 + c];
            bbpre[g * 3 + c] = a;
        }
    }
}

// column softmax over the 256 graphs (axis=0), 3 columns
__global__ __launch_bounds__(256) void bb_kernel(
        const float* __restrict__ bbpre, float* __restrict__ out_bb) {
    __shared__ float red[NG];
    int g = threadIdx.x;
#pragma unroll
    for (int c = 0; c < 3; c++) {
        float vv = bbpre[g * 3 + c];
        red[g] = vv;
        __syncthreads();
        for (int off = 128; off > 0; off >>= 1) {
            if (g < off) red[g] = fmaxf(red[g], red[g + off]);
            __syncthreads();
        }
        float m = red[0];
        __syncthreads();
        float e = __expf(vv - m);
        red[g] = e;
        __syncthreads();
        for (int off = 128; off > 0; off >>= 1) {
            if (g < off) red[g] += red[g + off];
            __syncthreads();
        }
        float ssum = red[0];
        __syncthreads();
        out_bb[g * 3 + c] = e / ssum;
    }
}

extern "C" void kernel_launch(void* const* d_in, const int* in_sizes, int n_in,
                              void* d_out, int out_size, void* d_ws, size_t ws_size,
                              hipStream_t stream) {
    const float* x   = (const float*)d_in[0];
    const int*   ei  = (const int*)d_in[1];    // [2,E] flat: row=ei[0..E), col=ei[E..2E)
    const int*   bat = (const int*)d_in[2];
    const float* W1  = (const float*)d_in[3];
    const float* b1  = (const float*)d_in[4];
    const float* W2  = (const float*)d_in[5];
    const float* b2  = (const float*)d_in[6];
    const float* Wg  = (const float*)d_in[7];
    const float* bg  = (const float*)d_in[8];
    const float* Wt  = (const float*)d_in[9];
    const float* bt  = (const float*)d_in[10];
    const float* Wn1 = (const float*)d_in[11];
    const float* bn1 = (const float*)d_in[12];
    const float* Wn2 = (const float*)d_in[13];
    const float* bn2 = (const float*)d_in[14];
    const float* Wb1 = (const float*)d_in[15];
    const float* bb1 = (const float*)d_in[16];
    const float* Wb2 = (const float*)d_in[17];
    const float* bb2 = (const float*)d_in[18];

    const int N = in_sizes[2];
    const int E = in_sizes[1] / 2;
    const int NB = (N + 255) >> 8;       // buckets of 256 nodes
    const int M = NB * NBLK;             // blockOff matrix size

    // workspace layout (4B units):
    // persistent: rowptr[N+1] | dinv[N] | adj[E] | bucketBase[NB+1] | bucketTot[NB]
    // transient (aliased union):
    //   build:   blockOff[M] | pairs[E]
    //   compute: bufA[32N] (hs1 bf16 -> h2[24N]f32 + v[N]f32) | bufB[12N] (hs2 bf16) | bbpre[768]
    auto rnd4 = [](size_t v) { return (v + 3) & ~(size_t)3; };
    size_t oRow = 0;
    size_t oDin = oRow + rnd4((size_t)N + 1);
    size_t oAdj = oDin + rnd4((size_t)N);
    size_t oBB  = oAdj + rnd4((size_t)E);
    size_t oTot = oBB + rnd4((size_t)NB + 1);
    size_t oT   = oTot + rnd4((size_t)NB);
    size_t oPar = oT + rnd4((size_t)M);

    int*   wsi     = (int*)d_ws;
    float* wsf     = (float*)d_ws;
    int*   rowptr  = wsi + oRow;
    float* dinv    = wsf + oDin;
    int*   adj     = wsi + oAdj;
    int*   bbase   = wsi + oBB;
    int*   btot    = wsi + oTot;
    int*   blkoff  = wsi + oT;
    int*   pairs   = wsi + oPar;
    float* bufA    = wsf + oT;                    // hs1 bf16 (16N f32-equiv); later h2 (24N) + v (N)
    ushort_t* hs1b = (ushort_t*)bufA;
    float* bufB    = wsf + oT + (size_t)32 * N;   // hs2 bf16 (12N f32-equiv)
    ushort_t* hs2b = (ushort_t*)bufB;
    float* bbpre   = wsf + oT + (size_t)56 * N;
    float* h2      = bufA;                        // hs1b dead once gather1 completes
    float* vbuf    = bufA + (size_t)24 * N;

    float* out_t  = (float*)d_out;          // [256,2]
    float* out_n  = out_t + 2 * NG;         // [N,1]
    float* out_bb = out_t + 2 * NG + N;     // [256,3]

    const int B = 256;

    // CSR build: bucketed counting sort; only tiny NB-sized scan is serial
    hipMemsetAsync(btot, 0, (size_t)NB * sizeof(int), stream);
    hist_bucket_kernel<<<NBLK, B, 0, stream>>>(ei + E, blkoff, btot, E, NB);
    tiny_scan_kernel<<<1, 512, 0, stream>>>(btot, bbase, NB);
    scatter_pairs_kernel<<<NBLK, B, 0, stream>>>(ei, blkoff, bbase, pairs, E, NB);
    csr_bucket_kernel<<<NB, B, 0, stream>>>(pairs, bbase, rowptr, adj, dinv, N, E);

    // GCN + heads (bf16 staging rows, fp32 accumulation)
    hs1_kernel<<<(N * 32 + B - 1) / B, B, 0, stream>>>(x, W1, dinv, hs1b, N);
    gather1_kernel<<<(N + 7) / 8, B, 0, stream>>>(rowptr, adj, hs1b, dinv, b1, W2, hs2b, N);
    gather2_kernel<<<(N + 7) / 8, B, 0, stream>>>(rowptr, adj, hs2b, dinv, b2,
                                                  Wn1, bn1, Wn2, bn2, h2, vbuf, N);
    graph_kernel<<<NG, B, 0, stream>>>(vbuf, h2, bat, Wg, bg, Wt, bt,
                                       Wb1, bb1, Wb2, bb2, out_t, out_n, bbpre, N);
    bb_kernel<<<1, B, 0, stream>>>(bbpre, out_bb);
}

// Round 6
// 360.630 us; speedup vs baseline: 2.8955x; 1.0594x over previous
//
#include <hip/hip_runtime.h>
#include <math.h>

#define NG 256     // NUM_GRAPHS
#define NBLK 256   // blocks in histogram / pair-scatter passes
// bucket = target >> 8  (256 nodes per bucket); supports N <= 131072 (src packs in 17 bits)

typedef unsigned short ushort_t;

__device__ __forceinline__ float lo16(unsigned u) { return __uint_as_float(u << 16); }
__device__ __forceinline__ float hi16(unsigned u) { return __uint_as_float(u & 0xffff0000u); }
__device__ __forceinline__ ushort_t f2bf(float x) {   // round-to-nearest-even
    unsigned u = __float_as_uint(x);
    unsigned r = (u + 0x7FFFu + ((u >> 16) & 1u)) >> 16;
    return (ushort_t)r;
}

// ---------------------------------------------------------------------------
// K1: per-block histogram of edge targets into NB buckets (LDS atomics), then
// reserve this block's range in each bucket via one global atomic per bucket.
__global__ __launch_bounds__(256) void hist_bucket_kernel(
        const int* __restrict__ col, int* __restrict__ blockOff,
        int* __restrict__ bucketTot, int E, int NB) {
    __shared__ int h[512];
    for (int t = threadIdx.x; t < NB; t += 256) h[t] = 0;
    __syncthreads();
    const int chunk = (E + NBLK - 1) / NBLK;
    const int beg = blockIdx.x * chunk;
    const int end = min(beg + chunk, E);
    for (int e = beg + threadIdx.x; e < end; e += 256)
        atomicAdd(&h[col[e] >> 8], 1);
    __syncthreads();
    for (int t = threadIdx.x; t < NB; t += 256) {
        int off = atomicAdd(&bucketTot[t], h[t]);   // reserve range (order arbitrary)
        blockOff[t * NBLK + blockIdx.x] = off;
    }
}

// K2: tiny exclusive scan over bucketTot[NB] -> bucketBase[NB+1]  (NB <= 512)
__global__ __launch_bounds__(512) void tiny_scan_kernel(
        const int* __restrict__ bucketTot, int* __restrict__ bucketBase, int NB) {
    __shared__ int part[512];
    const int t = threadIdx.x;
    int v = (t < NB) ? bucketTot[t] : 0;
    part[t] = v;
    __syncthreads();
    for (int o = 1; o < 512; o <<= 1) {
        int u = (t >= o) ? part[t - o] : 0;
        __syncthreads();
        part[t] += u;
        __syncthreads();
    }
    if (t < NB) bucketBase[t] = part[t] - v;   // exclusive
    if (t == NB) bucketBase[NB] = part[NB - 1];
    if (t == 511 && NB == 512) bucketBase[NB] = part[511];
}

// K3: scatter packed (local_tgt<<17 | src) pairs, grouped by bucket (LDS cursors)
__global__ __launch_bounds__(256) void scatter_pairs_kernel(
        const int* __restrict__ ei, const int* __restrict__ blockOff,
        const int* __restrict__ bucketBase, int* __restrict__ pairs, int E, int NB) {
    __shared__ int cur[512];
    for (int t = threadIdx.x; t < NB; t += 256)
        cur[t] = bucketBase[t] + blockOff[t * NBLK + blockIdx.x];
    __syncthreads();
    const int chunk = (E + NBLK - 1) / NBLK;
    const int beg = blockIdx.x * chunk;
    const int end = min(beg + chunk, E);
    for (int e = beg + threadIdx.x; e < end; e += 256) {
        int src = ei[e];
        int tgt = ei[E + e];
        int pos = atomicAdd(&cur[tgt >> 8], 1);
        pairs[pos] = (int)(((unsigned)(tgt & 255) << 17) | (unsigned)src);
    }
}

// K4: one block per bucket: local 256-bin histogram + scan -> rowptr, dinv, adj
__global__ __launch_bounds__(256) void csr_bucket_kernel(
        const int* __restrict__ pairs, const int* __restrict__ bucketBase,
        int* __restrict__ rowptr, int* __restrict__ adj,
        float* __restrict__ dinv, int N, int E) {
    __shared__ int h[256];
    __shared__ int sc[256];
    __shared__ int cur[256];
    const int b = blockIdx.x, t = threadIdx.x;
    const int base = bucketBase[b];
    const int end = bucketBase[b + 1];
    h[t] = 0;
    __syncthreads();
    for (int i = base + t; i < end; i += 256)
        atomicAdd(&h[(unsigned)pairs[i] >> 17], 1);
    __syncthreads();
    const int v = h[t];
    sc[t] = v;
    __syncthreads();
    for (int o = 1; o < 256; o <<= 1) {
        int u = (t >= o) ? sc[t - o] : 0;
        __syncthreads();
        sc[t] += u;
        __syncthreads();
    }
    const int ex = sc[t] - v;   // exclusive prefix within bucket
    const int node = (b << 8) + t;
    if (node < N) {
        rowptr[node] = base + ex;
        dinv[node] = rsqrtf((float)v + 1.0f);
    }
    cur[t] = base + ex;
    __syncthreads();
    for (int i = base + t; i < end; i += 256) {
        unsigned p = (unsigned)pairs[i];
        int pos = atomicAdd(&cur[p >> 17], 1);
        adj[pos] = (int)(p & 0x1FFFFu);
    }
    if (b == 0 && t == 0) rowptr[N] = E;
}

// ---------------------------------------------------------------------------
// hs1[i][f] = bf16( (sum_k x[i][k] * W1[k][f]) * dinv[i] )   (32 -> 32)
__global__ __launch_bounds__(256) void hs1_kernel(
        const float* __restrict__ x, const float* __restrict__ W,
        const float* __restrict__ dinv, ushort_t* __restrict__ hs, int N) {
    __shared__ float Ws[32 * 32];
    for (int t = threadIdx.x; t < 1024; t += blockDim.x) Ws[t] = W[t];
    __syncthreads();
    int gid = blockIdx.x * blockDim.x + threadIdx.x;
    if (gid >= N * 32) return;
    int i = gid >> 5, f = gid & 31;
    const float* xr = x + (size_t)i * 32;
    float acc = 0.f;
#pragma unroll
    for (int k = 0; k < 32; k++) acc += xr[k] * Ws[k * 32 + f];
    hs[gid] = f2bf(acc * dinv[i]);
}

// gather layer 1 (32 bf16 feats/row, packed uint2 loads: 8 lanes/row, 4 edges in
// flight per half-wave) + fused finalize + fused hs2 staging (padded to 32):
//   h1 = relu(dinv*(gather(hs1) + hs1_self) + b1)     (LDS only, fp32)
//   hs2[i][fo] = bf16( dinv[i] * sum_k h1[i][k] * W2[k][fo] )  fo<24, pad 0
__global__ __launch_bounds__(256) void gather1_kernel(
        const int* __restrict__ rowptr, const int* __restrict__ adj,
        const uint2* __restrict__ hs1q, const float* __restrict__ dinv,
        const float* __restrict__ b1, const float* __restrict__ W2,
        ushort_t* __restrict__ hs2out, int N) {
    __shared__ float W2s[32 * 24];
    __shared__ float b1s[32];
    __shared__ float h1row[8][32];
    const int tid = threadIdx.x;
    for (int t = tid; t < 768; t += 256) W2s[t] = W2[t];
    if (tid < 32) b1s[tid] = b1[tid];

    const int node = blockIdx.x * 8 + (tid >> 5);
    const int n = tid >> 5;
    const int l = tid & 31;
    const int f4 = l & 7;        // feature quad: features 4*f4 .. 4*f4+3
    const int e4 = l >> 3;       // edge slot 0..3
    const bool valid = node < N;

    int beg = 0, cnt = 0;
    if (valid) { beg = rowptr[node]; cnt = rowptr[node + 1] - beg; }
    const int* ap = adj + beg;
    float a0 = 0.f, a1 = 0.f, a2 = 0.f, a3 = 0.f;
    int j = 0;
    for (; j + 8 <= cnt; j += 8) {            // 8 edges/iter: 2 outstanding row loads/lane
        int s0 = ap[j + e4];
        int s1 = ap[j + 4 + e4];
        uint2 v0 = hs1q[(size_t)s0 * 8 + f4];
        uint2 v1 = hs1q[(size_t)s1 * 8 + f4];
        a0 += lo16(v0.x); a1 += hi16(v0.x); a2 += lo16(v0.y); a3 += hi16(v0.y);
        a0 += lo16(v1.x); a1 += hi16(v1.x); a2 += lo16(v1.y); a3 += hi16(v1.y);
    }
    for (; j + 4 <= cnt; j += 4) {
        int s0 = ap[j + e4];
        uint2 v0 = hs1q[(size_t)s0 * 8 + f4];
        a0 += lo16(v0.x); a1 += hi16(v0.x); a2 += lo16(v0.y); a3 += hi16(v0.y);
    }
    if (e4 < cnt - j) {                        // tail 0..3 edges
        int s0 = ap[j + e4];
        uint2 v0 = hs1q[(size_t)s0 * 8 + f4];
        a0 += lo16(v0.x); a1 += hi16(v0.x); a2 += lo16(v0.y); a3 += hi16(v0.y);
    }
    // fold the 4 edge slots (lane bits 3,4)
    a0 += __shfl_xor(a0, 8);  a0 += __shfl_xor(a0, 16);
    a1 += __shfl_xor(a1, 8);  a1 += __shfl_xor(a1, 16);
    a2 += __shfl_xor(a2, 8);  a2 += __shfl_xor(a2, 16);
    a3 += __shfl_xor(a3, 8);  a3 += __shfl_xor(a3, 16);

    __syncthreads();   // weight/bias staging visibility (all threads reach here)

    float di = 0.f;
    if (valid) {
        di = dinv[node];
        uint2 sv = hs1q[(size_t)node * 8 + f4];   // self-loop term
        if (e4 == 0) {
            h1row[n][4 * f4 + 0] = fmaxf(di * (a0 + lo16(sv.x)) + b1s[4 * f4 + 0], 0.f);
            h1row[n][4 * f4 + 1] = fmaxf(di * (a1 + hi16(sv.x)) + b1s[4 * f4 + 1], 0.f);
            h1row[n][4 * f4 + 2] = fmaxf(di * (a2 + lo16(sv.y)) + b1s[4 * f4 + 2], 0.f);
            h1row[n][4 * f4 + 3] = fmaxf(di * (a3 + hi16(sv.y)) + b1s[4 * f4 + 3], 0.f);
        }
    }
    // same-wave producer/consumer through LDS: no barrier needed
    if (valid) {
        const int f = l;
        float a = 0.f;
        if (f < 24) {
#pragma unroll
            for (int k = 0; k < 32; k++) a += h1row[n][k] * W2s[k * 24 + f];
        }
        hs2out[(size_t)node * 32 + f] = (f < 24) ? f2bf(a * di) : (ushort_t)0;
    }
}

// gather layer 2 (rows padded to 32 bf16, packed uint2 loads) + fused finalize +
// fused node-MLP:  h2 = relu(dinv*(gather+self)+b2);  v = relu(h2@Wn1+bn1)@Wn2+bn2
__global__ __launch_bounds__(256) void gather2_kernel(
        const int* __restrict__ rowptr, const int* __restrict__ adj,
        const uint2* __restrict__ hs2q, const float* __restrict__ dinv,
        const float* __restrict__ b2,
        const float* __restrict__ Wn1, const float* __restrict__ bn1,
        const float* __restrict__ Wn2, const float* __restrict__ bn2,
        float* __restrict__ h2out, float* __restrict__ vout, int N) {
    __shared__ float Wn1s[24 * 16];
    __shared__ float b2s[32], bn1s[16], Wn2s[16];
    __shared__ float h2row[8][32];
    const int tid = threadIdx.x;
    for (int t = tid; t < 384; t += 256) Wn1s[t] = Wn1[t];
    if (tid < 32) b2s[tid] = (tid < 24) ? b2[tid] : 0.f;
    if (tid < 16) { bn1s[tid] = bn1[tid]; Wn2s[tid] = Wn2[tid]; }

    const int node = blockIdx.x * 8 + (tid >> 5);
    const int n = tid >> 5;
    const int l = tid & 31;
    const int f4 = l & 7;
    const int e4 = l >> 3;
    const bool valid = node < N;

    int beg = 0, cnt = 0;
    if (valid) { beg = rowptr[node]; cnt = rowptr[node + 1] - beg; }
    const int* ap = adj + beg;
    float a0 = 0.f, a1 = 0.f, a2 = 0.f, a3 = 0.f;
    int j = 0;
    for (; j + 8 <= cnt; j += 8) {
        int s0 = ap[j + e4];
        int s1 = ap[j + 4 + e4];
        uint2 v0 = hs2q[(size_t)s0 * 8 + f4];
        uint2 v1 = hs2q[(size_t)s1 * 8 + f4];
        a0 += lo16(v0.x); a1 += hi16(v0.x); a2 += lo16(v0.y); a3 += hi16(v0.y);
        a0 += lo16(v1.x); a1 += hi16(v1.x); a2 += lo16(v1.y); a3 += hi16(v1.y);
    }
    for (; j + 4 <= cnt; j += 4) {
        int s0 = ap[j + e4];
        uint2 v0 = hs2q[(size_t)s0 * 8 + f4];
        a0 += lo16(v0.x); a1 += hi16(v0.x); a2 += lo16(v0.y); a3 += hi16(v0.y);
    }
    if (e4 < cnt - j) {
        int s0 = ap[j + e4];
        uint2 v0 = hs2q[(size_t)s0 * 8 + f4];
        a0 += lo16(v0.x); a1 += hi16(v0.x); a2 += lo16(v0.y); a3 += hi16(v0.y);
    }
    a0 += __shfl_xor(a0, 8);  a0 += __shfl_xor(a0, 16);
    a1 += __shfl_xor(a1, 8);  a1 += __shfl_xor(a1, 16);
    a2 += __shfl_xor(a2, 8);  a2 += __shfl_xor(a2, 16);
    a3 += __shfl_xor(a3, 8);  a3 += __shfl_xor(a3, 16);

    __syncthreads();   // weight/bias staging visibility

    if (valid) {
        float di = dinv[node];
        uint2 sv = hs2q[(size_t)node * 8 + f4];
        if (e4 == 0) {   // pad features (>=24): inputs all 0, b2s pad 0 -> h2 = 0
            h2row[n][4 * f4 + 0] = fmaxf(di * (a0 + lo16(sv.x)) + b2s[4 * f4 + 0], 0.f);
            h2row[n][4 * f4 + 1] = fmaxf(di * (a1 + hi16(sv.x)) + b2s[4 * f4 + 1], 0.f);
            h2row[n][4 * f4 + 2] = fmaxf(di * (a2 + lo16(sv.y)) + b2s[4 * f4 + 2], 0.f);
            h2row[n][4 * f4 + 3] = fmaxf(di * (a3 + hi16(sv.y)) + b2s[4 * f4 + 3], 0.f);
        }
    }
    // same-wave producer/consumer through LDS
    const int f = l;
    if (valid && f < 24) h2out[(size_t)node * 24 + f] = h2row[n][f];

    float val = 0.f;
    if (valid && f < 16) {
        float u = bn1s[f];
#pragma unroll
        for (int k = 0; k < 24; k++) u += h2row[n][k] * Wn1s[k * 16 + f];
        val = fmaxf(u, 0.f) * Wn2s[f];
    }
    val += __shfl_down(val, 8, 16);
    val += __shfl_down(val, 4, 16);
    val += __shfl_down(val, 2, 16);
    val += __shfl_down(val, 1, 16);
    if (valid && f == 0) vout[node] = val + bn2[0];
}

__device__ __forceinline__ int lower_bound_i(const int* __restrict__ a, int n, int key) {
    int lo = 0, hi = n;
    while (lo < hi) {
        int mid = (lo + hi) >> 1;
        if (a[mid] < key) lo = mid + 1; else hi = mid;
    }
    return lo;
}

// One block per graph (batch is sorted): segment softmax over nodes, mean pool,
// weighted pool, t-head, b-head pre-softmax. No global atomics.
__global__ __launch_bounds__(256) void graph_kernel(
        const float* __restrict__ v, const float* __restrict__ h2,
        const int* __restrict__ batch,
        const float* __restrict__ Wg, const float* __restrict__ bg,
        const float* __restrict__ Wt, const float* __restrict__ bt,
        const float* __restrict__ Wb1p, const float* __restrict__ bb1p,
        const float* __restrict__ Wb2p, const float* __restrict__ bb2p,
        float* __restrict__ out_t, float* __restrict__ out_n,
        float* __restrict__ bbpre, int N) {
    const int g = blockIdx.x;
    const int tid = threadIdx.x;
    const int lane = tid & 63;
    const int wid = tid >> 6;

    const int start = lower_bound_i(batch, N, g);
    const int end = lower_bound_i(batch, N, g + 1);

    __shared__ float sm[4];
    __shared__ float part[4][49];

    float m = -INFINITY;
    for (int idx = start + tid; idx < end; idx += 256) m = fmaxf(m, v[idx]);
#pragma unroll
    for (int off = 32; off > 0; off >>= 1) m = fmaxf(m, __shfl_down(m, off, 64));
    if (lane == 0) sm[wid] = m;
    __syncthreads();
    m = fmaxf(fmaxf(sm[0], sm[1]), fmaxf(sm[2], sm[3]));

    float s = 0.f;
    float hsum[24], wsum[24];
#pragma unroll
    for (int f = 0; f < 24; f++) { hsum[f] = 0.f; wsum[f] = 0.f; }
    for (int idx = start + tid; idx < end; idx += 256) {
        float e = __expf(v[idx] - m);
        s += e;
        const float4* hr = (const float4*)(h2 + (size_t)idx * 24);
#pragma unroll
        for (int q = 0; q < 6; q++) {
            float4 x4 = hr[q];
            hsum[4 * q] += x4.x;  wsum[4 * q] += e * x4.x;
            hsum[4 * q + 1] += x4.y; wsum[4 * q + 1] += e * x4.y;
            hsum[4 * q + 2] += x4.z; wsum[4 * q + 2] += e * x4.z;
            hsum[4 * q + 3] += x4.w; wsum[4 * q + 3] += e * x4.w;
        }
    }
#pragma unroll
    for (int off = 32; off > 0; off >>= 1) {
        s += __shfl_down(s, off, 64);
#pragma unroll
        for (int f = 0; f < 24; f++) {
            hsum[f] += __shfl_down(hsum[f], off, 64);
            wsum[f] += __shfl_down(wsum[f], off, 64);
        }
    }
    if (lane == 0) {
        part[wid][0] = s;
#pragma unroll
        for (int f = 0; f < 24; f++) { part[wid][1 + f] = hsum[f]; part[wid][25 + f] = wsum[f]; }
    }
    __syncthreads();
    const float stot = part[0][0] + part[1][0] + part[2][0] + part[3][0];
    const float invs = (stot > 0.f) ? 1.f / stot : 0.f;

    for (int idx = start + tid; idx < end; idx += 256)
        out_n[idx] = __expf(v[idx] - m) * invs;

    if (tid == 0) {
        float hsumT[24], wsumT[24];
#pragma unroll
        for (int f = 0; f < 24; f++) {
            hsumT[f] = part[0][1 + f] + part[1][1 + f] + part[2][1 + f] + part[3][1 + f];
            wsumT[f] = part[0][25 + f] + part[1][25 + f] + part[2][25 + f] + part[3][25 + f];
        }
        float cnt = (float)(end - start);
        float denom = fmaxf(cnt, 1.0f);

        float mean[24];
#pragma unroll
        for (int f = 0; f < 24; f++) mean[f] = hsumT[f] / denom;
        float gout[32];
        for (int o = 0; o < 32; o++) {
            float a = bg[o];
#pragma unroll
            for (int k = 0; k < 24; k++) a += mean[k] * Wg[k * 32 + o];
            gout[o] = a;
        }
        float t0 = bt[0], t1 = bt[1];
#pragma unroll
        for (int k = 0; k < 32; k++) { t0 += gout[k] * Wt[k * 2]; t1 += gout[k] * Wt[k * 2 + 1]; }
        float tm = fmaxf(t0, t1);
        float e0 = __expf(t0 - tm), e1 = __expf(t1 - tm);
        float ts = e0 + e1;
        out_t[g * 2 + 0] = e0 / ts;
        out_t[g * 2 + 1] = e1 / ts;

        float bf[24];
#pragma unroll
        for (int f = 0; f < 24; f++) bf[f] = wsumT[f] * invs;
        float u[16];
        for (int j = 0; j < 16; j++) {
            float a = bb1p[j];
#pragma unroll
            for (int k = 0; k < 24; k++) a += bf[k] * Wb1p[k * 16 + j];
            u[j] = fmaxf(a, 0.f);
        }
        for (int c = 0; c < 3; c++) {
            float a = bb2p[c];
#pragma unroll
            for (int j = 0; j < 16; j++) a += u[j] * Wb2p[j * 3 + c];
            bbpre[g * 3 + c] = a;
        }
    }
}

// column softmax over the 256 graphs (axis=0), 3 columns
__global__ __launch_bounds__(256) void bb_kernel(
        const float* __restrict__ bbpre, float* __restrict__ out_bb) {
    __shared__ float red[NG];
    int g = threadIdx.x;
#pragma unroll
    for (int c = 0; c < 3; c++) {
        float vv = bbpre[g * 3 + c];
        red[g] = vv;
        __syncthreads();
        for (int off = 128; off > 0; off >>= 1) {
            if (g < off) red[g] = fmaxf(red[g], red[g + off]);
            __syncthreads();
        }
        float m = red[0];
        __syncthreads();
        float e = __expf(vv - m);
        red[g] = e;
        __syncthreads();
        for (int off = 128; off > 0; off >>= 1) {
            if (g < off) red[g] += red[g + off];
            __syncthreads();
        }
        float ssum = red[0];
        __syncthreads();
        out_bb[g * 3 + c] = e / ssum;
    }
}

extern "C" void kernel_launch(void* const* d_in, const int* in_sizes, int n_in,
                              void* d_out, int out_size, void* d_ws, size_t ws_size,
                              hipStream_t stream) {
    const float* x   = (const float*)d_in[0];
    const int*   ei  = (const int*)d_in[1];    // [2,E] flat: row=ei[0..E), col=ei[E..2E)
    const int*   bat = (const int*)d_in[2];
    const float* W1  = (const float*)d_in[3];
    const float* b1  = (const float*)d_in[4];
    const float* W2  = (const float*)d_in[5];
    const float* b2  = (const float*)d_in[6];
    const float* Wg  = (const float*)d_in[7];
    const float* bg  = (const float*)d_in[8];
    const float* Wt  = (const float*)d_in[9];
    const float* bt  = (const float*)d_in[10];
    const float* Wn1 = (const float*)d_in[11];
    const float* bn1 = (const float*)d_in[12];
    const float* Wn2 = (const float*)d_in[13];
    const float* bn2 = (const float*)d_in[14];
    const float* Wb1 = (const float*)d_in[15];
    const float* bb1 = (const float*)d_in[16];
    const float* Wb2 = (const float*)d_in[17];
    const float* bb2 = (const float*)d_in[18];

    const int N = in_sizes[2];
    const int E = in_sizes[1] / 2;
    const int NB = (N + 255) >> 8;       // buckets of 256 nodes
    const int M = NB * NBLK;             // blockOff matrix size

    // workspace layout (4B units):
    // persistent: rowptr[N+1] | dinv[N] | adj[E] | bucketBase[NB+1] | bucketTot[NB]
    // transient (aliased union):
    //   build:   blockOff[M] | pairs[E]
    //   compute: bufA[32N] (hs1 bf16 16N -> h2 24N f32 + v N f32) | bufB[16N] (hs2 bf16, padded 32/row) | bbpre[768]
    auto rnd4 = [](size_t v) { return (v + 3) & ~(size_t)3; };
    size_t oRow = 0;
    size_t oDin = oRow + rnd4((size_t)N + 1);
    size_t oAdj = oDin + rnd4((size_t)N);
    size_t oBB  = oAdj + rnd4((size_t)E);
    size_t oTot = oBB + rnd4((size_t)NB + 1);
    size_t oT   = oTot + rnd4((size_t)NB);
    size_t oPar = oT + rnd4((size_t)M);

    int*   wsi     = (int*)d_ws;
    float* wsf     = (float*)d_ws;
    int*   rowptr  = wsi + oRow;
    float* dinv    = wsf + oDin;
    int*   adj     = wsi + oAdj;
    int*   bbase   = wsi + oBB;
    int*   btot    = wsi + oTot;
    int*   blkoff  = wsi + oT;
    int*   pairs   = wsi + oPar;
    float* bufA    = wsf + oT;                    // hs1 bf16 (16N units); later h2 (24N) + v (N)
    ushort_t* hs1b = (ushort_t*)bufA;
    float* bufB    = wsf + oT + (size_t)32 * N;   // hs2 bf16 padded (16N units)
    ushort_t* hs2b = (ushort_t*)bufB;
    float* bbpre   = wsf + oT + (size_t)48 * N;
    float* h2      = bufA;                        // hs1b dead once gather1 completes
    float* vbuf    = bufA + (size_t)24 * N;

    float* out_t  = (float*)d_out;          // [256,2]
    float* out_n  = out_t + 2 * NG;         // [N,1]
    float* out_bb = out_t + 2 * NG + N;     // [256,3]

    const int B = 256;

    // CSR build: bucketed counting sort; only tiny NB-sized scan is serial
    hipMemsetAsync(btot, 0, (size_t)NB * sizeof(int), stream);
    hist_bucket_kernel<<<NBLK, B, 0, stream>>>(ei + E, blkoff, btot, E, NB);
    tiny_scan_kernel<<<1, 512, 0, stream>>>(btot, bbase, NB);
    scatter_pairs_kernel<<<NBLK, B, 0, stream>>>(ei, blkoff, bbase, pairs, E, NB);
    csr_bucket_kernel<<<NB, B, 0, stream>>>(pairs, bbase, rowptr, adj, dinv, N, E);

    // GCN + heads (bf16 staging rows, packed uint2 gathers, fp32 accumulation)
    hs1_kernel<<<(N * 32 + B - 1) / B, B, 0, stream>>>(x, W1, dinv, hs1b, N);
    gather1_kernel<<<(N + 7) / 8, B, 0, stream>>>(rowptr, adj, (const uint2*)hs1b,
                                                  dinv, b1, W2, hs2b, N);
    gather2_kernel<<<(N + 7) / 8, B, 0, stream>>>(rowptr, adj, (const uint2*)hs2b,
                                                  dinv, b2, Wn1, bn1, Wn2, bn2, h2, vbuf, N);
    graph_kernel<<<NG, B, 0, stream>>>(vbuf, h2, bat, Wg, bg, Wt, bt,
                                       Wb1, bb1, Wb2, bb2, out_t, out_n, bbpre, N);
    bb_kernel<<<1, B, 0, stream>>>(bbpre, out_bb);
}